// Round 1
// baseline (1284.667 us; speedup 1.0000x reference)
//
#include <hip/hip_runtime.h>
#include <math.h>

#define NN 307
#define UU 100
#define DD 3
#define FF 103   // UU + DD

// ---------------------------------------------------------------------------
// CSR build: deterministic (no atomics). One block; thread t owns dst node t.
// Edge list = [src/dst pairs 0..E-1] ++ [self loops n=0..N-1] (reference order).
// ---------------------------------------------------------------------------
__global__ __launch_bounds__(320)
void build_csr_k(const int* __restrict__ src, const int* __restrict__ dst,
                 int E, int* offs /*NN+1*/, int* eidx /*E+NN*/)
{
    constexpr int CAP = 4608;
    __shared__ int sd[CAP];
    __shared__ int ss[CAP];
    const int tid = threadIdx.x;
    const int Etot = E + NN;
    const bool staged = (E <= CAP);
    if (staged) {
        for (int e = tid; e < E; e += 320) { sd[e] = dst[e]; ss[e] = src[e]; }
    }
    __syncthreads();
    if (tid < NN) {
        int c = 0;
        for (int e = 0; e < Etot; ++e) {
            int d = (e < E) ? (staged ? sd[e] : dst[e]) : (e - E);
            if (d == tid) ++c;
        }
        offs[tid + 1] = c;
    }
    __syncthreads();
    if (tid == 0) {
        offs[0] = 0;
        for (int i = 1; i <= NN; ++i) offs[i] += offs[i - 1];
    }
    __syncthreads();
    if (tid < NN) {
        int w = offs[tid];
        for (int e = 0; e < Etot; ++e) {
            int d = (e < E) ? (staged ? sd[e] : dst[e]) : (e - E);
            if (d == tid) {
                int s = (e < E) ? (staged ? ss[e] : src[e]) : (e - E);
                eidx[w++] = s;
            }
        }
    }
}

// ---------------------------------------------------------------------------
// GATv2 edge phase. One wave per (b, d). Online softmax: after the 64-lane
// butterfly sum the edge score is wave-uniform, so max/denom/aggregate are a
// single rescaled pass over incoming edges. Writes st (may alias xr: each
// wave reads only its own xr[b,d] before writing st[b,d]).
// ---------------------------------------------------------------------------
__global__ __launch_bounds__(256)
void gat_k(const float* __restrict__ xl, const float* xr,
           const int* __restrict__ offs, const int* __restrict__ eidx,
           const float* __restrict__ att, const float* __restrict__ gb,
           const float* __restrict__ bgc, float* stout)
{
    const int b   = blockIdx.x;
    const int wid = blockIdx.y * 4 + (threadIdx.x >> 6);   // 0..31
    const int lane = threadIdx.x & 63;
    const int u0 = lane, u1 = lane + 64;
    const bool h1 = (u1 < UU);
    const float att0 = att[u0];
    const float att1 = h1 ? att[u1] : 0.f;
    const float bs0 = gb[u0] + bgc[u0];
    const float bs1 = h1 ? (gb[u1] + bgc[u1]) : 0.f;
    const float* xlb = xl + (size_t)b * NN * UU;
    const float* xrb = xr + (size_t)b * NN * UU;
    float* stb = stout + (size_t)b * NN * UU;

    for (int d = wid; d < NN; d += 32) {
        const int e0 = offs[d], e1 = offs[d + 1];
        const float xr0 = xrb[d * UU + u0];
        const float xr1 = h1 ? xrb[d * UU + u1] : 0.f;
        float mx = -1e30f, dn = 0.f, a0 = 0.f, a1 = 0.f;
        for (int e = e0; e < e1; ++e) {
            const int s = eidx[e];
            const float m0 = xlb[s * UU + u0];
            const float m1 = h1 ? xlb[s * UU + u1] : 0.f;
            float v0 = m0 + xr0; v0 = v0 > 0.f ? v0 : 0.2f * v0;
            float v1 = m1 + xr1; v1 = v1 > 0.f ? v1 : 0.2f * v1;
            float p = v0 * att0 + v1 * att1;
            #pragma unroll
            for (int m = 1; m < 64; m <<= 1) p += __shfl_xor(p, m, 64);
            float ex;
            if (p > mx) {                 // wave-uniform branch
                const float sc = expf(mx - p);
                dn *= sc; a0 *= sc; a1 *= sc;
                mx = p; ex = 1.f;
            } else {
                ex = expf(p - mx);
            }
            dn += ex; a0 += ex * m0; a1 += ex * m1;
        }
        const float inv = 1.f / dn;
        stb[d * UU + u0] = a0 * inv + bs0;
        if (h1) stb[d * UU + u1] = a1 * inv + bs1;
    }
}

// ---------------------------------------------------------------------------
// Generic (78592 x 103) @ (103 x 100) GEMM with implicit row-concat gather.
// x row = [A1 row (c1) | A2 row (c2)]. W accessed as W[k*ldW + colOff + col]
// so GRU1's 200-wide output runs as two column-slice launches.
// MODE 0: out = acc                       (xl / xr)
// MODE 1: out = sigmoid(acc+b) * st       (r*st)
// MODE 2: out = sigmoid(acc+b)            (u, staged in d_out)
// MODE 3: c = tanh(acc+b); out = u*st+(1-u)*c   (final; uarr/out0 alias d_out)
// ---------------------------------------------------------------------------
template<int MODE>
__global__ __launch_bounds__(256)
void gemm_k(const float* __restrict__ A1, int c1,
            const float* __restrict__ A2, int c2,
            const float* __restrict__ W, int ldW, int colOff,
            const float* __restrict__ bias,
            const float* st, const float* uarr,
            float* out0, int M)
{
    __shared__ float xs[64][FF];
    const int tid = threadIdx.x;
    const int tx = tid & 15, ty = tid >> 4;
    const int block_row = blockIdx.x * 64;

    for (int t = tid; t < 64 * FF; t += 256) {
        const int r = t / FF, k = t % FF;
        int row = block_row + r; if (row >= M) row = M - 1;
        const float v = (k < c1) ? A1[(size_t)row * c1 + k]
                                 : A2[(size_t)row * c2 + (k - c1)];
        xs[r][k] = v;
    }
    __syncthreads();

    float acc[4][7] = {};
    for (int k = 0; k < FF; ++k) {
        float xv[4];
        #pragma unroll
        for (int i = 0; i < 4; ++i) xv[i] = xs[ty * 4 + i][k];
        #pragma unroll
        for (int j = 0; j < 7; ++j) {
            const int col = tx + 16 * j;
            const float wv = (col < UU) ? W[(size_t)k * ldW + colOff + col] : 0.f;
            #pragma unroll
            for (int i = 0; i < 4; ++i) acc[i][j] += xv[i] * wv;
        }
    }

    #pragma unroll
    for (int j = 0; j < 7; ++j) {
        const int col = tx + 16 * j;
        if (col >= UU) continue;
        const float bv = (MODE == 0) ? 0.f : bias[col];
        #pragma unroll
        for (int i = 0; i < 4; ++i) {
            const int row = block_row + ty * 4 + i;
            if (row >= M) continue;
            const size_t o = (size_t)row * UU + col;
            const float a = acc[i][j] + bv;
            if (MODE == 0) {
                out0[o] = a;
            } else if (MODE == 1) {
                const float sg = 1.f / (1.f + expf(-a));
                out0[o] = sg * st[o];
            } else if (MODE == 2) {
                out0[o] = 1.f / (1.f + expf(-a));
            } else {
                const float c = tanhf(a);
                const float u = uarr[o];
                out0[o] = u * st[o] + (1.f - u) * c;
            }
        }
    }
}

// ---------------------------------------------------------------------------
extern "C" void kernel_launch(void* const* d_in, const int* in_sizes, int n_in,
                              void* d_out, int out_size, void* d_ws, size_t ws_size,
                              hipStream_t stream)
{
    const float* inputs   = (const float*)d_in[0];
    const float* state    = (const float*)d_in[1];
    const int*   src      = (const int*)  d_in[2];
    const int*   dst      = (const int*)  d_in[3];
    const float* Wl       = (const float*)d_in[4];
    const float* Wr       = (const float*)d_in[5];
    const float* att      = (const float*)d_in[6];
    const float* gat_bias = (const float*)d_in[7];
    const float* bias_gc  = (const float*)d_in[8];
    const float* Wg1      = (const float*)d_in[9];
    const float* bg1      = (const float*)d_in[10];
    const float* Wg2      = (const float*)d_in[11];
    const float* bg2      = (const float*)d_in[12];

    const int E = in_sizes[2];
    const int B = in_sizes[1] / (NN * UU);
    const int M = B * NN;

    char* ws = (char*)d_ws;
    const size_t S = (size_t)M * UU * sizeof(float);
    float* xl   = (float*)ws;              // later reused as r*st
    float* xr   = (float*)(ws + S);        // later reused as st
    int*   offs = (int*)(ws + 2 * S);
    int*   eidx = offs + (NN + 1);
    float* stb  = xr;                      // st aliases xr (safe: per-(b,d) wave)
    float* rst  = xl;                      // r*st overwrites xl (xl dead after gat)
    float* out  = (float*)d_out;           // u staged here, then final in place

    const int mb = (M + 63) / 64;

    build_csr_k<<<1, 320, 0, stream>>>(src, dst, E, offs, eidx);

    // xl = [state|inputs] @ Wl ; xr = [state|inputs] @ Wr
    gemm_k<0><<<mb, 256, 0, stream>>>(state, UU, inputs, DD, Wl, UU, 0,
                                      nullptr, nullptr, nullptr, xl, M);
    gemm_k<0><<<mb, 256, 0, stream>>>(state, UU, inputs, DD, Wr, UU, 0,
                                      nullptr, nullptr, nullptr, xr, M);

    // st = GATv2(xl, xr) + gat_bias + bias_gc   (writes into xr buffer)
    gat_k<<<dim3(B, 8), 256, 0, stream>>>(xl, xr, offs, eidx,
                                          att, gat_bias, bias_gc, stb);

    // r*st = sigmoid([inputs|st] @ Wg1[:, :100] + b) * st   -> xl buffer
    gemm_k<1><<<mb, 256, 0, stream>>>(inputs, DD, stb, UU, Wg1, 2 * UU, 0,
                                      bg1, stb, nullptr, rst, M);
    // u = sigmoid([inputs|st] @ Wg1[:, 100:] + b)           -> d_out (scratch)
    gemm_k<2><<<mb, 256, 0, stream>>>(inputs, DD, stb, UU, Wg1, 2 * UU, UU,
                                      bg1 + UU, nullptr, nullptr, out, M);
    // c = tanh([inputs|r*st] @ Wg2 + b); out = u*st + (1-u)*c
    gemm_k<3><<<mb, 256, 0, stream>>>(inputs, DD, rst, UU, Wg2, UU, 0,
                                      bg2, stb, out, out, M);
}

// Round 2
// 469.056 us; speedup vs baseline: 2.7388x; 2.7388x over previous
//
#include <hip/hip_runtime.h>
#include <math.h>

#define NN 307
#define UU 100
#define DD 3
#define FF 103   // UU + DD

// ---------------------------------------------------------------------------
// CSR build, parallel + deterministic. One wave per dst node.
// Edge list = [src/dst pairs 0..E-1] ++ [self loops n=0..N-1] (reference order).
// csr_fill_k preserves edge order via ballot+popcount ranking, so the CSR is
// bit-identical to a serial stable scan.
// ---------------------------------------------------------------------------
__global__ __launch_bounds__(64)
void csr_count_k(const int* __restrict__ dst, int E, int* offs /*NN+1*/)
{
    const int d = blockIdx.x;
    const int lane = threadIdx.x;
    const int Etot = E + NN;
    int c = 0;
    for (int base = 0; base < Etot; base += 64) {
        const int e = base + lane;
        if (e < Etot) {
            const int de = (e < E) ? dst[e] : (e - E);
            c += (de == d) ? 1 : 0;
        }
    }
    #pragma unroll
    for (int m = 1; m < 64; m <<= 1) c += __shfl_xor(c, m, 64);
    if (lane == 0) {
        offs[d + 1] = c;
        if (d == 0) offs[0] = 0;
    }
}

__global__ void csr_scan_k(int* offs)
{
    if (threadIdx.x == 0) {
        int acc = 0;
        for (int i = 1; i <= NN; ++i) { acc += offs[i]; offs[i] = acc; }
    }
}

__global__ __launch_bounds__(64)
void csr_fill_k(const int* __restrict__ src, const int* __restrict__ dst,
                int E, const int* __restrict__ offs, int* eidx)
{
    const int d = blockIdx.x;
    const int lane = threadIdx.x;
    const int Etot = E + NN;
    int w = offs[d];
    for (int base = 0; base < Etot; base += 64) {
        const int e = base + lane;
        bool match = false;
        int se = 0;
        if (e < Etot) {
            const int de = (e < E) ? dst[e] : (e - E);
            se           = (e < E) ? src[e] : (e - E);
            match = (de == d);
        }
        const unsigned long long mask = __ballot(match);
        if (match) {
            const int pos = w + __popcll(mask & ((1ULL << lane) - 1ULL));
            eidx[pos] = se;
        }
        w += __popcll(mask);
    }
}

// ---------------------------------------------------------------------------
// GATv2 edge phase. One wave per (b, d). Online softmax: after the 64-lane
// butterfly sum the edge score is wave-uniform, so max/denom/aggregate are a
// single rescaled pass over incoming edges. Writes st (may alias xr: each
// wave reads only its own xr[b,d] before writing st[b,d]).
// ---------------------------------------------------------------------------
__global__ __launch_bounds__(256)
void gat_k(const float* __restrict__ xl, const float* xr,
           const int* __restrict__ offs, const int* __restrict__ eidx,
           const float* __restrict__ att, const float* __restrict__ gb,
           const float* __restrict__ bgc, float* stout)
{
    const int b   = blockIdx.x;
    const int wid = blockIdx.y * 4 + (threadIdx.x >> 6);   // 0..31
    const int lane = threadIdx.x & 63;
    const int u0 = lane, u1 = lane + 64;
    const bool h1 = (u1 < UU);
    const float att0 = att[u0];
    const float att1 = h1 ? att[u1] : 0.f;
    const float bs0 = gb[u0] + bgc[u0];
    const float bs1 = h1 ? (gb[u1] + bgc[u1]) : 0.f;
    const float* xlb = xl + (size_t)b * NN * UU;
    const float* xrb = xr + (size_t)b * NN * UU;
    float* stb = stout + (size_t)b * NN * UU;

    for (int d = wid; d < NN; d += 32) {
        const int e0 = offs[d], e1 = offs[d + 1];
        const float xr0 = xrb[d * UU + u0];
        const float xr1 = h1 ? xrb[d * UU + u1] : 0.f;
        float mx = -1e30f, dn = 0.f, a0 = 0.f, a1 = 0.f;
        for (int e = e0; e < e1; ++e) {
            const int s = eidx[e];
            const float m0 = xlb[s * UU + u0];
            const float m1 = h1 ? xlb[s * UU + u1] : 0.f;
            float v0 = m0 + xr0; v0 = v0 > 0.f ? v0 : 0.2f * v0;
            float v1 = m1 + xr1; v1 = v1 > 0.f ? v1 : 0.2f * v1;
            float p = v0 * att0 + v1 * att1;
            #pragma unroll
            for (int m = 1; m < 64; m <<= 1) p += __shfl_xor(p, m, 64);
            float ex;
            if (p > mx) {                 // wave-uniform branch
                const float sc = expf(mx - p);
                dn *= sc; a0 *= sc; a1 *= sc;
                mx = p; ex = 1.f;
            } else {
                ex = expf(p - mx);
            }
            dn += ex; a0 += ex * m0; a1 += ex * m1;
        }
        const float inv = 1.f / dn;
        stb[d * UU + u0] = a0 * inv + bs0;
        if (h1) stb[d * UU + u1] = a1 * inv + bs1;
    }
}

// ---------------------------------------------------------------------------
// Generic (78592 x 103) @ (103 x 100) GEMM with implicit row-concat gather.
// x row = [A1 row (c1) | A2 row (c2)]. W accessed as W[k*ldW + colOff + col]
// so GRU1's 200-wide output runs as two column-slice launches.
// MODE 0: out = acc                       (xl / xr)
// MODE 1: out = sigmoid(acc+b) * st       (r*st)
// MODE 2: out = sigmoid(acc+b)            (u, staged in d_out)
// MODE 3: c = tanh(acc+b); out = u*st+(1-u)*c   (final; uarr/out0 alias d_out)
// ---------------------------------------------------------------------------
template<int MODE>
__global__ __launch_bounds__(256)
void gemm_k(const float* __restrict__ A1, int c1,
            const float* __restrict__ A2, int c2,
            const float* __restrict__ W, int ldW, int colOff,
            const float* __restrict__ bias,
            const float* st, const float* uarr,
            float* out0, int M)
{
    __shared__ float xs[64][FF];
    const int tid = threadIdx.x;
    const int tx = tid & 15, ty = tid >> 4;
    const int block_row = blockIdx.x * 64;

    for (int t = tid; t < 64 * FF; t += 256) {
        const int r = t / FF, k = t % FF;
        int row = block_row + r; if (row >= M) row = M - 1;
        const float v = (k < c1) ? A1[(size_t)row * c1 + k]
                                 : A2[(size_t)row * c2 + (k - c1)];
        xs[r][k] = v;
    }
    __syncthreads();

    float acc[4][7] = {};
    for (int k = 0; k < FF; ++k) {
        float xv[4];
        #pragma unroll
        for (int i = 0; i < 4; ++i) xv[i] = xs[ty * 4 + i][k];
        #pragma unroll
        for (int j = 0; j < 7; ++j) {
            const int col = tx + 16 * j;
            const float wv = (col < UU) ? W[(size_t)k * ldW + colOff + col] : 0.f;
            #pragma unroll
            for (int i = 0; i < 4; ++i) acc[i][j] += xv[i] * wv;
        }
    }

    #pragma unroll
    for (int j = 0; j < 7; ++j) {
        const int col = tx + 16 * j;
        if (col >= UU) continue;
        const float bv = (MODE == 0) ? 0.f : bias[col];
        #pragma unroll
        for (int i = 0; i < 4; ++i) {
            const int row = block_row + ty * 4 + i;
            if (row >= M) continue;
            const size_t o = (size_t)row * UU + col;
            const float a = acc[i][j] + bv;
            if (MODE == 0) {
                out0[o] = a;
            } else if (MODE == 1) {
                const float sg = 1.f / (1.f + expf(-a));
                out0[o] = sg * st[o];
            } else if (MODE == 2) {
                out0[o] = 1.f / (1.f + expf(-a));
            } else {
                const float c = tanhf(a);
                const float u = uarr[o];
                out0[o] = u * st[o] + (1.f - u) * c;
            }
        }
    }
}

// ---------------------------------------------------------------------------
extern "C" void kernel_launch(void* const* d_in, const int* in_sizes, int n_in,
                              void* d_out, int out_size, void* d_ws, size_t ws_size,
                              hipStream_t stream)
{
    const float* inputs   = (const float*)d_in[0];
    const float* state    = (const float*)d_in[1];
    const int*   src      = (const int*)  d_in[2];
    const int*   dst      = (const int*)  d_in[3];
    const float* Wl       = (const float*)d_in[4];
    const float* Wr       = (const float*)d_in[5];
    const float* att      = (const float*)d_in[6];
    const float* gat_bias = (const float*)d_in[7];
    const float* bias_gc  = (const float*)d_in[8];
    const float* Wg1      = (const float*)d_in[9];
    const float* bg1      = (const float*)d_in[10];
    const float* Wg2      = (const float*)d_in[11];
    const float* bg2      = (const float*)d_in[12];

    const int E = in_sizes[2];
    const int B = in_sizes[1] / (NN * UU);
    const int M = B * NN;

    char* ws = (char*)d_ws;
    const size_t S = (size_t)M * UU * sizeof(float);
    float* xl   = (float*)ws;              // later reused as r*st
    float* xr   = (float*)(ws + S);        // later reused as st
    int*   offs = (int*)(ws + 2 * S);
    int*   eidx = offs + (NN + 1);
    float* stb  = xr;                      // st aliases xr (safe: per-(b,d) wave)
    float* rst  = xl;                      // r*st overwrites xl (xl dead after gat)
    float* out  = (float*)d_out;           // u staged here, then final in place

    const int mb = (M + 63) / 64;

    csr_count_k<<<NN, 64, 0, stream>>>(dst, E, offs);
    csr_scan_k<<<1, 64, 0, stream>>>(offs);
    csr_fill_k<<<NN, 64, 0, stream>>>(src, dst, E, offs, eidx);

    // xl = [state|inputs] @ Wl ; xr = [state|inputs] @ Wr
    gemm_k<0><<<mb, 256, 0, stream>>>(state, UU, inputs, DD, Wl, UU, 0,
                                      nullptr, nullptr, nullptr, xl, M);
    gemm_k<0><<<mb, 256, 0, stream>>>(state, UU, inputs, DD, Wr, UU, 0,
                                      nullptr, nullptr, nullptr, xr, M);

    // st = GATv2(xl, xr) + gat_bias + bias_gc   (writes into xr buffer)
    gat_k<<<dim3(B, 8), 256, 0, stream>>>(xl, xr, offs, eidx,
                                          att, gat_bias, bias_gc, stb);

    // r*st = sigmoid([inputs|st] @ Wg1[:, :100] + b) * st   -> xl buffer
    gemm_k<1><<<mb, 256, 0, stream>>>(inputs, DD, stb, UU, Wg1, 2 * UU, 0,
                                      bg1, stb, nullptr, rst, M);
    // u = sigmoid([inputs|st] @ Wg1[:, 100:] + b)           -> d_out (scratch)
    gemm_k<2><<<mb, 256, 0, stream>>>(inputs, DD, stb, UU, Wg1, 2 * UU, UU,
                                      bg1 + UU, nullptr, nullptr, out, M);
    // c = tanh([inputs|r*st] @ Wg2 + b); out = u*st + (1-u)*c
    gemm_k<3><<<mb, 256, 0, stream>>>(inputs, DD, rst, UU, Wg2, UU, 0,
                                      bg2, stb, out, out, M);
}

// Round 3
// 410.775 us; speedup vs baseline: 3.1274x; 1.1419x over previous
//
#include <hip/hip_runtime.h>
#include <math.h>

#define NN 307
#define UU 100
#define DD 3
#define FF 103          // UU + DD
#define KP 128          // padded K
#define NP 112          // padded N
#define MT 128          // rows per GEMM block
#define UNIT_W (NP*KP)  // f16 elements per packed weight unit
#define SC_STRIDE 4608  // per-sample score stride (>= E+NN)

typedef _Float16 f16;
typedef f16  f16x8 __attribute__((ext_vector_type(8)));
typedef float f32x4 __attribute__((ext_vector_type(4)));

// LDS index (in f16 units) for [row][k] tiles with T2 XOR swizzle:
// byte = row*256 + kb*16, kb = k/8, swizzled kb ^= (row&7) -> <=2-way conflicts.
__device__ __forceinline__ int swz(int row, int kb) {
    return row * KP + ((kb ^ (row & 7)) << 3);
}

// ---------------------------------------------------------------------------
// Pack all weights to f16, padded [112 cols][128 k], GRU rows permuted so the
// concat layout is always [big(100) | inputs(3) | zeros]:
// unit 0: Wl, 1: Wr, 2: Wg1[:, :100], 3: Wg1[:, 100:], 4: Wg2.
// ---------------------------------------------------------------------------
__global__ __launch_bounds__(256)
void pack_w_k(const float* __restrict__ Wl, const float* __restrict__ Wr,
              const float* __restrict__ Wg1, const float* __restrict__ Wg2,
              f16* __restrict__ Wt)
{
    const int total = 5 * UNIT_W;
    for (int idx = blockIdx.x * 256 + threadIdx.x; idx < total; idx += gridDim.x * 256) {
        const int u = idx / UNIT_W;
        const int rem = idx - u * UNIT_W;
        const int col = rem >> 7;        // 0..111
        const int k   = rem & (KP - 1);  // 0..127
        float v = 0.f;
        if (col < UU && k < FF) {
            if (u == 0)      v = Wl[k * UU + col];
            else if (u == 1) v = Wr[k * UU + col];
            else {
                // our k: 0..99 = hidden, 100..102 = inputs; source rows: 0..2 inputs, 3..102 hidden
                const int kk = (k < UU) ? (k + DD) : (k - UU);
                if (u == 2)      v = Wg1[kk * (2 * UU) + col];
                else if (u == 3) v = Wg1[kk * (2 * UU) + UU + col];
                else             v = Wg2[kk * UU + col];
            }
        }
        Wt[idx] = (f16)v;
    }
}

// ---------------------------------------------------------------------------
// CSR build, parallel + deterministic (order-preserving). Also emits ddst
// (dst per CSR position) for the edge-parallel score kernel.
// ---------------------------------------------------------------------------
__global__ __launch_bounds__(64)
void csr_count_k(const int* __restrict__ dst, int E, int* offs)
{
    const int d = blockIdx.x;
    const int lane = threadIdx.x;
    const int Etot = E + NN;
    int c = 0;
    for (int base = 0; base < Etot; base += 64) {
        const int e = base + lane;
        if (e < Etot) {
            const int de = (e < E) ? dst[e] : (e - E);
            c += (de == d) ? 1 : 0;
        }
    }
    #pragma unroll
    for (int m = 1; m < 64; m <<= 1) c += __shfl_xor(c, m, 64);
    if (lane == 0) {
        offs[d + 1] = c;
        if (d == 0) offs[0] = 0;
    }
}

__global__ void csr_scan_k(int* offs)
{
    if (threadIdx.x == 0) {
        int acc = 0;
        for (int i = 1; i <= NN; ++i) { acc += offs[i]; offs[i] = acc; }
    }
}

__global__ __launch_bounds__(64)
void csr_fill_k(const int* __restrict__ src, const int* __restrict__ dst,
                int E, const int* __restrict__ offs,
                int* eidx, int* ddst)
{
    const int d = blockIdx.x;
    const int lane = threadIdx.x;
    const int Etot = E + NN;
    int w = offs[d];
    for (int base = 0; base < Etot; base += 64) {
        const int e = base + lane;
        bool match = false;
        int se = 0;
        if (e < Etot) {
            const int de = (e < E) ? dst[e] : (e - E);
            se           = (e < E) ? src[e] : (e - E);
            match = (de == d);
        }
        const unsigned long long mask = __ballot(match);
        if (match) {
            const int pos = w + __popcll(mask & ((1ULL << lane) - 1ULL));
            eidx[pos] = se;
            ddst[pos] = d;
        }
        w += __popcll(mask);
    }
}

// ---------------------------------------------------------------------------
// GAT phase A: one thread per (b, edge). Full 100-d dot per lane, no shuffles.
// ---------------------------------------------------------------------------
__global__ __launch_bounds__(256)
void score_k(const float* __restrict__ xl, const float* __restrict__ xr,
             const int* __restrict__ eidx, const int* __restrict__ ddst,
             const float* __restrict__ att, int Etot, float* __restrict__ scores)
{
    const int b = blockIdx.y;
    const int i = blockIdx.x * 256 + threadIdx.x;
    if (i >= Etot) return;
    const int s = eidx[i];
    const int d = ddst[i];
    const float* xls = xl + ((size_t)b * NN + s) * UU;
    const float* xrd = xr + ((size_t)b * NN + d) * UU;
    float p = 0.f;
    #pragma unroll 5
    for (int u = 0; u < UU; u += 4) {
        const float4 a  = *(const float4*)(xls + u);
        const float4 r  = *(const float4*)(xrd + u);
        const float4 at = *(const float4*)(att + u);
        float v;
        v = a.x + r.x; v = v > 0.f ? v : 0.2f * v; p += v * at.x;
        v = a.y + r.y; v = v > 0.f ? v : 0.2f * v; p += v * at.y;
        v = a.z + r.z; v = v > 0.f ? v : 0.2f * v; p += v * at.z;
        v = a.w + r.w; v = v > 0.f ? v : 0.2f * v; p += v * at.w;
    }
    scores[(size_t)b * SC_STRIDE + i] = p;
}

// ---------------------------------------------------------------------------
// GAT phase B: one wave per (b, d). Chunk-level softmax (12 butterflies per d,
// not per edge), then lanes-as-features coalesced aggregate.
// st = segsum(alpha*m) + gat_bias + bias_gc. May write over xr (only xl read).
// ---------------------------------------------------------------------------
__global__ __launch_bounds__(256)
void gatagg_k(const float* __restrict__ xl, const float* __restrict__ scores,
              const int* __restrict__ offs, const int* __restrict__ eidx,
              const float* __restrict__ gb, const float* __restrict__ bgc,
              float* __restrict__ stout)
{
    __shared__ float al[4][64];
    const int b    = blockIdx.x;
    const int wv   = threadIdx.x >> 6;
    const int wid  = blockIdx.y * 4 + wv;   // 0..31
    const int lane = threadIdx.x & 63;
    const int u0 = lane, u1 = lane + 64;
    const bool h1 = (u1 < UU);
    const float bs0 = gb[u0] + bgc[u0];
    const float bs1 = h1 ? (gb[u1] + bgc[u1]) : 0.f;
    const float* xlb = xl + (size_t)b * NN * UU;
    const float* scb = scores + (size_t)b * SC_STRIDE;
    float* stb = stout + (size_t)b * NN * UU;

    for (int d = wid; d < NN; d += 32) {
        const int e0 = offs[d], e1 = offs[d + 1];
        float mx = -1e30f, dn = 0.f, a0 = 0.f, a1 = 0.f;
        for (int c0 = e0; c0 < e1; c0 += 64) {
            const int n = min(64, e1 - c0);
            const float sc = (lane < n) ? scb[c0 + lane] : -1e30f;
            float cm = sc;
            #pragma unroll
            for (int m = 1; m < 64; m <<= 1) cm = fmaxf(cm, __shfl_xor(cm, m, 64));
            const float nm = fmaxf(mx, cm);
            const float rs = __expf(mx - nm);          // 0 on first chunk
            const float ex = (lane < n) ? __expf(sc - nm) : 0.f;
            float cs = ex;
            #pragma unroll
            for (int m = 1; m < 64; m <<= 1) cs += __shfl_xor(cs, m, 64);
            dn = dn * rs + cs;
            a0 *= rs; a1 *= rs;
            al[wv][lane] = ex;
            for (int i = 0; i < n; ++i) {
                const float w = al[wv][i];             // LDS broadcast (free)
                const int s = eidx[c0 + i];            // wave-uniform -> scalar
                const float* m = xlb + (size_t)s * UU;
                a0 += w * m[u0];
                if (h1) a1 += w * m[u1];
            }
            mx = nm;
        }
        const float inv = 1.f / dn;
        stb[d * UU + u0] = a0 * inv + bs0;
        if (h1) stb[d * UU + u1] = a1 * inv + bs1;
    }
}

// ---------------------------------------------------------------------------
// f16 MFMA GEMM: out[M,100] = [big(100)|inputs(3)|0...] @ Wt_unit (K=128,N=112)
// Block: 256 threads (4 waves), 128 rows. A and W tiles in LDS, XOR-swizzled.
// Per wave: 2 row-tiles x 7 col-tiles, K-loop = 4 steps of 32.
// MODE 0: y=0 -> outA = acc (xl); y=1 -> outB = acc (xr)
// MODE 1: y=0 -> outA = sigmoid(acc+biasA)*st (r*st); y=1 -> outB = sigmoid(acc+biasB) (u)
// MODE 2: c = tanh(acc+biasA); outA = u*st + (1-u)*c
// ---------------------------------------------------------------------------
template<int MODE>
__global__ __launch_bounds__(256)
void gemm16_k(const float* __restrict__ big, const float* __restrict__ inp,
              const f16* __restrict__ Wt,   // base of unit for y=0; y adds UNIT_W
              const float* __restrict__ biasA, const float* __restrict__ biasB,
              const float* __restrict__ st, const float* __restrict__ uarr,
              float* __restrict__ outA, float* __restrict__ outB, int M)
{
    __shared__ f16 As[MT * KP];   // 32 KB
    __shared__ f16 Bs[NP * KP];   // 28 KB
    const int tid = threadIdx.x;
    const int w   = tid >> 6;
    const int l   = tid & 63;
    const int rb  = blockIdx.x * MT;
    const int y   = blockIdx.y;

    // ---- stage W tile (linear global -> swizzled LDS) ----
    const f16* Wg = Wt + (size_t)y * UNIT_W;
    for (int idx = tid; idx < NP * KP / 8; idx += 256) {
        const int row = idx >> 4, kb = idx & 15;
        *(f16x8*)&Bs[swz(row, kb)] = *(const f16x8*)&Wg[idx * 8];
    }

    // ---- stage A tile: rows [rb, rb+128), convert f32->f16, swizzled ----
    // lane -> (4 rows x 16 kb) per pass; 8 passes cover 32 rows per wave.
    for (int p = 0; p < 8; ++p) {
        const int rl = w * 32 + p * 4 + (l >> 4);
        const int kb = l & 15;
        int row = rb + rl; if (row >= M) row = M - 1;
        f16x8 v;
        if (kb < 12) {
            const float4 x0 = *(const float4*)(big + (size_t)row * UU + kb * 8);
            const float4 x1 = *(const float4*)(big + (size_t)row * UU + kb * 8 + 4);
            v[0]=(f16)x0.x; v[1]=(f16)x0.y; v[2]=(f16)x0.z; v[3]=(f16)x0.w;
            v[4]=(f16)x1.x; v[5]=(f16)x1.y; v[6]=(f16)x1.z; v[7]=(f16)x1.w;
        } else if (kb == 12) {
            const float4 x0 = *(const float4*)(big + (size_t)row * UU + 96);
            v[0]=(f16)x0.x; v[1]=(f16)x0.y; v[2]=(f16)x0.z; v[3]=(f16)x0.w;
            v[4]=(f16)inp[(size_t)row * DD + 0];
            v[5]=(f16)inp[(size_t)row * DD + 1];
            v[6]=(f16)inp[(size_t)row * DD + 2];
            v[7]=(f16)0.f;
        } else {
            v = (f16x8)(f16)0.f;
        }
        *(f16x8*)&As[swz(rl, kb)] = v;
    }
    __syncthreads();

    // ---- MFMA main loop ----
    const int lr = l & 15;   // row-in-tile (A) / col-in-tile (B,C)
    const int lk = l >> 4;   // k-block within step
    f32x4 acc[2][7];
    #pragma unroll
    for (int t = 0; t < 2; ++t)
        #pragma unroll
        for (int j = 0; j < 7; ++j) acc[t][j] = (f32x4)0.f;

    #pragma unroll
    for (int s = 0; s < 4; ++s) {
        const int kb = s * 4 + lk;
        f16x8 af[2];
        #pragma unroll
        for (int t = 0; t < 2; ++t)
            af[t] = *(const f16x8*)&As[swz(w * 32 + t * 16 + lr, kb)];
        #pragma unroll
        for (int j = 0; j < 7; ++j) {
            const f16x8 bf = *(const f16x8*)&Bs[swz(j * 16 + lr, kb)];
            #pragma unroll
            for (int t = 0; t < 2; ++t)
                acc[t][j] = __builtin_amdgcn_mfma_f32_16x16x32_f16(af[t], bf, acc[t][j], 0, 0, 0);
        }
    }

    // ---- epilogue: C layout col = lane&15, row = (lane>>4)*4 + reg ----
    #pragma unroll
    for (int t = 0; t < 2; ++t) {
        #pragma unroll
        for (int j = 0; j < 7; ++j) {
            const int col = j * 16 + lr;
            if (col >= UU) continue;
            const int row0 = rb + w * 32 + t * 16 + (l >> 4) * 4;
            #pragma unroll
            for (int r = 0; r < 4; ++r) {
                const int row = row0 + r;
                if (row >= M) continue;
                const size_t o = (size_t)row * UU + col;
                const float a = acc[t][j][r];
                if (MODE == 0) {
                    (y ? outB : outA)[o] = a;
                } else if (MODE == 1) {
                    if (y == 0) {
                        const float sg = 1.f / (1.f + __expf(-(a + biasA[col])));
                        outA[o] = sg * st[o];
                    } else {
                        outB[o] = 1.f / (1.f + __expf(-(a + biasB[col])));
                    }
                } else {
                    const float c = tanhf(a + biasA[col]);
                    const float u = uarr[o];
                    outA[o] = u * st[o] + (1.f - u) * c;
                }
            }
        }
    }
}

// ---------------------------------------------------------------------------
extern "C" void kernel_launch(void* const* d_in, const int* in_sizes, int n_in,
                              void* d_out, int out_size, void* d_ws, size_t ws_size,
                              hipStream_t stream)
{
    const float* inputs   = (const float*)d_in[0];
    const float* state    = (const float*)d_in[1];
    const int*   src      = (const int*)  d_in[2];
    const int*   dst      = (const int*)  d_in[3];
    const float* Wl       = (const float*)d_in[4];
    const float* Wr       = (const float*)d_in[5];
    const float* att      = (const float*)d_in[6];
    const float* gat_bias = (const float*)d_in[7];
    const float* bias_gc  = (const float*)d_in[8];
    const float* Wg1      = (const float*)d_in[9];
    const float* bg1      = (const float*)d_in[10];
    const float* Wg2      = (const float*)d_in[11];
    const float* bg2      = (const float*)d_in[12];

    const int E = in_sizes[2];
    const int B = in_sizes[1] / (NN * UU);
    const int M = B * NN;
    const int Etot = E + NN;

    char* ws = (char*)d_ws;
    const size_t S = (size_t)M * UU * sizeof(float);
    float* xl   = (float*)ws;                    // later reused as r*st
    float* xr   = (float*)(ws + S);              // later reused as st
    f16*   Wt   = (f16*)(ws + 2 * S);            // packed weights (143 KB)
    int*   offs = (int*)(ws + 2 * S + 5 * UNIT_W * sizeof(f16));
    int*   eidx = offs + (NN + 1);
    int*   ddst = eidx + (Etot + 64);
    float* stb  = xr;                            // st overwrites xr
    float* rst  = xl;                            // r*st overwrites xl
    float* out  = (float*)d_out;
    float* scores = (float*)d_out;               // scores staged in d_out (dead before u)

    const int mb = (M + MT - 1) / MT;

    pack_w_k<<<56, 256, 0, stream>>>(Wl, Wr, Wg1, Wg2, Wt);
    csr_count_k<<<NN, 64, 0, stream>>>(dst, E, offs);
    csr_scan_k<<<1, 64, 0, stream>>>(offs);
    csr_fill_k<<<NN, 64, 0, stream>>>(src, dst, E, offs, eidx, ddst);

    // xl = [state|inputs] @ Wl ; xr = [state|inputs] @ Wr
    gemm16_k<0><<<dim3(mb, 2), 256, 0, stream>>>(state, inputs, Wt,
                                                 nullptr, nullptr, nullptr, nullptr,
                                                 xl, xr, M);
    // GAT scores (edge-parallel), then softmax+aggregate -> st (in xr buffer)
    score_k<<<dim3((Etot + 255) / 256, B), 256, 0, stream>>>(xl, xr, eidx, ddst,
                                                             att, Etot, scores);
    gatagg_k<<<dim3(B, 8), 256, 0, stream>>>(xl, scores, offs, eidx,
                                             gat_bias, bias_gc, stb);

    // gru1: y=0 -> rst = sigmoid(.)*st ; y=1 -> u = sigmoid(.) (staged in d_out)
    gemm16_k<1><<<dim3(mb, 2), 256, 0, stream>>>(stb, inputs, Wt + 2 * (size_t)UNIT_W,
                                                 bg1, bg1 + UU, stb, nullptr,
                                                 rst, out, M);
    // gru2: c = tanh(.); out = u*st + (1-u)*c
    gemm16_k<2><<<dim3(mb, 1), 256, 0, stream>>>(rst, inputs, Wt + 4 * (size_t)UNIT_W,
                                                 bg2, nullptr, stb, out,
                                                 out, nullptr, M);
}

// Round 4
// 322.741 us; speedup vs baseline: 3.9805x; 1.2728x over previous
//
#include <hip/hip_runtime.h>
#include <math.h>

#define NN 307
#define UU 100
#define DD 3
#define UP 104          // padded f16 activation row stride (208 B, 16B-aligned)
#define KP 128          // padded K
#define NP 112          // padded N
#define MT 128          // rows per GEMM block
#define UNIT_W (NP*KP)  // f16 elements per packed weight unit
#define SC_STRIDE 4608  // per-sample score stride (>= E+NN)

typedef _Float16 f16;
typedef f16  f16x2 __attribute__((ext_vector_type(2)));
typedef f16  f16x4 __attribute__((ext_vector_type(4)));
typedef f16  f16x8 __attribute__((ext_vector_type(8)));
typedef float f32x4 __attribute__((ext_vector_type(4)));

// LDS index (f16 units) for [row][k] tiles, T2 XOR swizzle on the 16B chunk.
__device__ __forceinline__ int swz(int row, int kb) {
    return row * KP + ((kb ^ (row & 7)) << 3);
}

// ---------------------------------------------------------------------------
// Pack weights to f16 [112 cols][128 k]; GRU rows permuted to [big(100)|inp(3)].
// unit 0: Wl, 1: Wr, 2: Wg1[:, :100], 3: Wg1[:, 100:], 4: Wg2.
// ---------------------------------------------------------------------------
__global__ __launch_bounds__(256)
void pack_w_k(const float* __restrict__ Wl, const float* __restrict__ Wr,
              const float* __restrict__ Wg1, const float* __restrict__ Wg2,
              f16* __restrict__ Wt)
{
    const int total = 5 * UNIT_W;
    for (int idx = blockIdx.x * 256 + threadIdx.x; idx < total; idx += gridDim.x * 256) {
        const int u = idx / UNIT_W;
        const int rem = idx - u * UNIT_W;
        const int col = rem >> 7;
        const int k   = rem & (KP - 1);
        float v = 0.f;
        if (col < UU && k < UU + DD) {
            if (u == 0)      v = Wl[k * UU + col];
            else if (u == 1) v = Wr[k * UU + col];
            else {
                const int kk = (k < UU) ? (k + DD) : (k - UU);
                if (u == 2)      v = Wg1[kk * (2 * UU) + col];
                else if (u == 3) v = Wg1[kk * (2 * UU) + UU + col];
                else             v = Wg2[kk * UU + col];
            }
        }
        Wt[idx] = (f16)v;
    }
}

// ---------------------------------------------------------------------------
// CSR build, parallel + deterministic (order-preserving).
// ---------------------------------------------------------------------------
__global__ __launch_bounds__(64)
void csr_count_k(const int* __restrict__ dst, int E, int* offs)
{
    const int d = blockIdx.x;
    const int lane = threadIdx.x;
    const int Etot = E + NN;
    int c = 0;
    for (int base = 0; base < Etot; base += 64) {
        const int e = base + lane;
        if (e < Etot) {
            const int de = (e < E) ? dst[e] : (e - E);
            c += (de == d) ? 1 : 0;
        }
    }
    #pragma unroll
    for (int m = 1; m < 64; m <<= 1) c += __shfl_xor(c, m, 64);
    if (lane == 0) {
        offs[d + 1] = c;
        if (d == 0) offs[0] = 0;
    }
}

__global__ void csr_scan_k(int* offs)
{
    if (threadIdx.x == 0) {
        int acc = 0;
        for (int i = 1; i <= NN; ++i) { acc += offs[i]; offs[i] = acc; }
    }
}

__global__ __launch_bounds__(64)
void csr_fill_k(const int* __restrict__ src, const int* __restrict__ dst,
                int E, const int* __restrict__ offs,
                int* eidx, int* ddst)
{
    const int d = blockIdx.x;
    const int lane = threadIdx.x;
    const int Etot = E + NN;
    int w = offs[d];
    for (int base = 0; base < Etot; base += 64) {
        const int e = base + lane;
        bool match = false;
        int se = 0;
        if (e < Etot) {
            const int de = (e < E) ? dst[e] : (e - E);
            se           = (e < E) ? src[e] : (e - E);
            match = (de == d);
        }
        const unsigned long long mask = __ballot(match);
        if (match) {
            const int pos = w + __popcll(mask & ((1ULL << lane) - 1ULL));
            eidx[pos] = se;
            ddst[pos] = d;
        }
        w += __popcll(mask);
    }
}

// ---------------------------------------------------------------------------
// GAT phase A: one thread per (b, edge); full 100-d dot, f16x8 loads.
// ---------------------------------------------------------------------------
__global__ __launch_bounds__(256)
void score_k(const f16* __restrict__ xl, const f16* __restrict__ xr,
             const int* __restrict__ eidx, const int* __restrict__ ddst,
             const float* __restrict__ att, int Etot, float* __restrict__ scores)
{
    const int b = blockIdx.y;
    const int i = blockIdx.x * 256 + threadIdx.x;
    if (i >= Etot) return;
    const int s = eidx[i];
    const int d = ddst[i];
    const f16* xls = xl + ((size_t)b * NN + s) * UP;
    const f16* xrd = xr + ((size_t)b * NN + d) * UP;
    float p = 0.f;
    #pragma unroll
    for (int u = 0; u < 96; u += 8) {
        const f16x8 a = *(const f16x8*)(xls + u);
        const f16x8 r = *(const f16x8*)(xrd + u);
        #pragma unroll
        for (int j = 0; j < 8; ++j) {
            float v = (float)a[j] + (float)r[j];
            v = v > 0.f ? v : 0.2f * v;
            p += v * att[u + j];
        }
    }
    {
        const f16x4 a = *(const f16x4*)(xls + 96);
        const f16x4 r = *(const f16x4*)(xrd + 96);
        #pragma unroll
        for (int j = 0; j < 4; ++j) {
            float v = (float)a[j] + (float)r[j];
            v = v > 0.f ? v : 0.2f * v;
            p += v * att[96 + j];
        }
    }
    scores[(size_t)b * SC_STRIDE + i] = p;
}

// ---------------------------------------------------------------------------
// GAT phase B: one wave per (b, d). Chunk-level online softmax (12 butterflies
// per chunk). Inner aggregate: ex + eidx staged in LDS (broadcast reads),
// lanes 0..49 each own feature pair (2l, 2l+1) -> one f16x2 load per edge,
// unrolled x4 for MLP. Writes st (f16, UP-stride) over the xr buffer.
// ---------------------------------------------------------------------------
__global__ __launch_bounds__(256)
void gatagg_k(const f16* __restrict__ xl, const float* __restrict__ scores,
              const int* __restrict__ offs, const int* __restrict__ eidx,
              const float* __restrict__ gb, const float* __restrict__ bgc,
              f16* __restrict__ stout)
{
    __shared__ float al[4][64];
    __shared__ int   sl[4][64];
    const int b    = blockIdx.x;
    const int wv   = threadIdx.x >> 6;
    const int wid  = blockIdx.y * 4 + wv;   // 0..31
    const int lane = threadIdx.x & 63;
    const bool act = (lane < 50);
    const int f0 = 2 * lane;
    float bs0 = 0.f, bs1 = 0.f;
    if (act) { bs0 = gb[f0] + bgc[f0]; bs1 = gb[f0 + 1] + bgc[f0 + 1]; }
    const f16* xlb = xl + (size_t)b * NN * UP;
    const float* scb = scores + (size_t)b * SC_STRIDE;
    f16* stb = stout + (size_t)b * NN * UP;

    for (int d = wid; d < NN; d += 32) {
        const int e0 = offs[d], e1 = offs[d + 1];
        float mx = -1e30f, dn = 0.f, a0 = 0.f, a1 = 0.f;
        for (int c0 = e0; c0 < e1; c0 += 64) {
            const int n = min(64, e1 - c0);
            const float sc = (lane < n) ? scb[c0 + lane] : -1e30f;
            const int  se  = (lane < n) ? eidx[c0 + lane] : 0;
            float cm = sc;
            #pragma unroll
            for (int m = 1; m < 64; m <<= 1) cm = fmaxf(cm, __shfl_xor(cm, m, 64));
            const float nm = fmaxf(mx, cm);
            const float rs = __expf(mx - nm);          // 0 on first chunk
            const float ex = (lane < n) ? __expf(sc - nm) : 0.f;
            float cs = ex;
            #pragma unroll
            for (int m = 1; m < 64; m <<= 1) cs += __shfl_xor(cs, m, 64);
            dn = dn * rs + cs;
            a0 *= rs; a1 *= rs;
            al[wv][lane] = ex;
            sl[wv][lane] = se;
            int i = 0;
            for (; i + 4 <= n; i += 4) {
                const float w0 = al[wv][i];     const int s0 = sl[wv][i];
                const float w1 = al[wv][i + 1]; const int s1 = sl[wv][i + 1];
                const float w2 = al[wv][i + 2]; const int s2 = sl[wv][i + 2];
                const float w3 = al[wv][i + 3]; const int s3 = sl[wv][i + 3];
                if (act) {
                    const f16x2 m0 = *(const f16x2*)(xlb + (size_t)s0 * UP + f0);
                    const f16x2 m1 = *(const f16x2*)(xlb + (size_t)s1 * UP + f0);
                    const f16x2 m2 = *(const f16x2*)(xlb + (size_t)s2 * UP + f0);
                    const f16x2 m3 = *(const f16x2*)(xlb + (size_t)s3 * UP + f0);
                    a0 += w0 * (float)m0[0] + w1 * (float)m1[0]
                        + w2 * (float)m2[0] + w3 * (float)m3[0];
                    a1 += w0 * (float)m0[1] + w1 * (float)m1[1]
                        + w2 * (float)m2[1] + w3 * (float)m3[1];
                }
            }
            for (; i < n; ++i) {
                const float w0 = al[wv][i]; const int s0 = sl[wv][i];
                if (act) {
                    const f16x2 m0 = *(const f16x2*)(xlb + (size_t)s0 * UP + f0);
                    a0 += w0 * (float)m0[0];
                    a1 += w0 * (float)m0[1];
                }
            }
            mx = nm;
        }
        if (act) {
            const float inv = 1.f / dn;
            f16x2 o;
            o[0] = (f16)(a0 * inv + bs0);
            o[1] = (f16)(a1 * inv + bs1);
            *(f16x2*)(stb + (size_t)d * UP + f0) = o;
        }
    }
}

// ---------------------------------------------------------------------------
// f16 MFMA GEMM: out[M,100] = [big(100)|inputs(3)|0...] @ Wt_unit (K=128,N=112)
// AF16: A ("big") operand is f16 UP-stride (0 -> f32 UU-stride, i.e. state).
// MODE 0: y=0 -> outA = acc (xl,f16); y=1 -> outB = acc (xr,f16)
// MODE 1: y=0 -> outA = sigmoid(acc+biasA)*st (f16); y=1 -> outB = sigmoid(acc+biasB) (f16)
// MODE 2: c = tanh(acc+biasA); outF = u*st + (1-u)*c  (f32, d_out)
// ---------------------------------------------------------------------------
template<int MODE, int AF16>
__global__ __launch_bounds__(256)
void gemm16_k(const void* __restrict__ bigv, const float* __restrict__ inp,
              const f16* __restrict__ Wt,
              const float* __restrict__ biasA, const float* __restrict__ biasB,
              const f16* __restrict__ st, const f16* __restrict__ uarr,
              f16* __restrict__ outA, f16* __restrict__ outB,
              float* __restrict__ outF, int M)
{
    __shared__ f16 As[MT * KP];   // 32 KB
    __shared__ f16 Bs[NP * KP];   // 28 KB
    const int tid = threadIdx.x;
    const int w   = tid >> 6;
    const int l   = tid & 63;
    const int rb  = blockIdx.x * MT;
    const int y   = blockIdx.y;

    // ---- stage W tile ----
    const f16* Wg = Wt + (size_t)y * UNIT_W;
    for (int idx = tid; idx < NP * KP / 8; idx += 256) {
        const int row = idx >> 4, kb = idx & 15;
        *(f16x8*)&Bs[swz(row, kb)] = *(const f16x8*)&Wg[idx * 8];
    }

    // ---- stage A tile ----
    for (int p = 0; p < 8; ++p) {
        const int rl = w * 32 + p * 4 + (l >> 4);
        const int kb = l & 15;
        int row = rb + rl; if (row >= M) row = M - 1;
        f16x8 v = (f16x8)(f16)0.f;
        if (AF16) {
            const f16* bh = (const f16*)bigv + (size_t)row * UP;
            if (kb < 12) {
                v = *(const f16x8*)(bh + kb * 8);
            } else if (kb == 12) {
                v = *(const f16x8*)(bh + 96);       // 96..99 real, 100..103 pad
                v[4] = (f16)inp[(size_t)row * DD + 0];
                v[5] = (f16)inp[(size_t)row * DD + 1];
                v[6] = (f16)inp[(size_t)row * DD + 2];
                v[7] = (f16)0.f;
            }
        } else {
            const float* bf = (const float*)bigv + (size_t)row * UU;
            if (kb < 12) {
                const float4 x0 = *(const float4*)(bf + kb * 8);
                const float4 x1 = *(const float4*)(bf + kb * 8 + 4);
                v[0]=(f16)x0.x; v[1]=(f16)x0.y; v[2]=(f16)x0.z; v[3]=(f16)x0.w;
                v[4]=(f16)x1.x; v[5]=(f16)x1.y; v[6]=(f16)x1.z; v[7]=(f16)x1.w;
            } else if (kb == 12) {
                const float4 x0 = *(const float4*)(bf + 96);
                v[0]=(f16)x0.x; v[1]=(f16)x0.y; v[2]=(f16)x0.z; v[3]=(f16)x0.w;
                v[4]=(f16)inp[(size_t)row * DD + 0];
                v[5]=(f16)inp[(size_t)row * DD + 1];
                v[6]=(f16)inp[(size_t)row * DD + 2];
                v[7]=(f16)0.f;
            }
        }
        *(f16x8*)&As[swz(rl, kb)] = v;
    }
    __syncthreads();

    // ---- MFMA main loop ----
    const int lr = l & 15;
    const int lk = l >> 4;
    f32x4 acc[2][7];
    #pragma unroll
    for (int t = 0; t < 2; ++t)
        #pragma unroll
        for (int j = 0; j < 7; ++j) acc[t][j] = (f32x4)0.f;

    #pragma unroll
    for (int s = 0; s < 4; ++s) {
        const int kb = s * 4 + lk;
        f16x8 af[2];
        #pragma unroll
        for (int t = 0; t < 2; ++t)
            af[t] = *(const f16x8*)&As[swz(w * 32 + t * 16 + lr, kb)];
        #pragma unroll
        for (int j = 0; j < 7; ++j) {
            const f16x8 bf = *(const f16x8*)&Bs[swz(j * 16 + lr, kb)];
            #pragma unroll
            for (int t = 0; t < 2; ++t)
                acc[t][j] = __builtin_amdgcn_mfma_f32_16x16x32_f16(af[t], bf, acc[t][j], 0, 0, 0);
        }
    }

    // ---- epilogue: C layout col = lane&15, row = (lane>>4)*4 + reg ----
    #pragma unroll
    for (int t = 0; t < 2; ++t) {
        #pragma unroll
        for (int j = 0; j < 7; ++j) {
            const int col = j * 16 + lr;
            if (col >= UU) continue;
            const int row0 = rb + w * 32 + t * 16 + (l >> 4) * 4;
            #pragma unroll
            for (int r = 0; r < 4; ++r) {
                const int row = row0 + r;
                if (row >= M) continue;
                const float a = acc[t][j][r];
                const size_t oh = (size_t)row * UP + col;
                if (MODE == 0) {
                    (y ? outB : outA)[oh] = (f16)a;
                } else if (MODE == 1) {
                    if (y == 0) {
                        const float sg = 1.f / (1.f + __expf(-(a + biasA[col])));
                        outA[oh] = (f16)(sg * (float)st[oh]);
                    } else {
                        outB[oh] = (f16)(1.f / (1.f + __expf(-(a + biasB[col]))));
                    }
                } else {
                    const float c = tanhf(a + biasA[col]);
                    const float u = (float)uarr[oh];
                    const float s = (float)st[oh];
                    outF[(size_t)row * UU + col] = u * s + (1.f - u) * c;
                }
            }
        }
    }
}

// ---------------------------------------------------------------------------
extern "C" void kernel_launch(void* const* d_in, const int* in_sizes, int n_in,
                              void* d_out, int out_size, void* d_ws, size_t ws_size,
                              hipStream_t stream)
{
    const float* inputs   = (const float*)d_in[0];
    const float* state    = (const float*)d_in[1];
    const int*   src      = (const int*)  d_in[2];
    const int*   dst      = (const int*)  d_in[3];
    const float* Wl       = (const float*)d_in[4];
    const float* Wr       = (const float*)d_in[5];
    const float* att      = (const float*)d_in[6];
    const float* gat_bias = (const float*)d_in[7];
    const float* bias_gc  = (const float*)d_in[8];
    const float* Wg1      = (const float*)d_in[9];
    const float* bg1      = (const float*)d_in[10];
    const float* Wg2      = (const float*)d_in[11];
    const float* bg2      = (const float*)d_in[12];

    const int E = in_sizes[2];
    const int B = in_sizes[1] / (NN * UU);
    const int M = B * NN;
    const int Etot = E + NN;

    char* ws = (char*)d_ws;
    const size_t SH = (size_t)M * UP * sizeof(f16);   // f16 activation buffer
    f16* xl_h = (f16*)ws;                             // later reused as r*st
    f16* xr_h = (f16*)(ws + SH);                      // later reused as st
    f16* u_h  = (f16*)(ws + 2 * SH);
    f16* Wt   = (f16*)(ws + 3 * SH);
    int* offs = (int*)(ws + 3 * SH + 5 * UNIT_W * sizeof(f16));
    int* eidx = offs + (NN + 1);
    int* ddst = eidx + (Etot + 64);
    f16* st_h  = xr_h;                                // st overwrites xr
    f16* rst_h = xl_h;                                // r*st overwrites xl
    float* out = (float*)d_out;
    float* scores = (float*)d_out;                    // dead before out write

    const int mb = (M + MT - 1) / MT;

    pack_w_k<<<56, 256, 0, stream>>>(Wl, Wr, Wg1, Wg2, Wt);
    csr_count_k<<<NN, 64, 0, stream>>>(dst, E, offs);
    csr_scan_k<<<1, 64, 0, stream>>>(offs);
    csr_fill_k<<<NN, 64, 0, stream>>>(src, dst, E, offs, eidx, ddst);

    // xl = [state|inputs] @ Wl ; xr = [state|inputs] @ Wr   (f16 out)
    gemm16_k<0, 0><<<dim3(mb, 2), 256, 0, stream>>>(state, inputs, Wt,
        nullptr, nullptr, nullptr, nullptr, xl_h, xr_h, nullptr, M);

    // GAT scores (edge-parallel) then softmax+aggregate -> st
    score_k<<<dim3((Etot + 255) / 256, B), 256, 0, stream>>>(xl_h, xr_h, eidx,
        ddst, att, Etot, scores);
    gatagg_k<<<dim3(B, 8), 256, 0, stream>>>(xl_h, scores, offs, eidx,
        gat_bias, bias_gc, st_h);

    // gru1: y=0 -> rst = sigmoid(.)*st ; y=1 -> u = sigmoid(.)
    gemm16_k<1, 1><<<dim3(mb, 2), 256, 0, stream>>>(st_h, inputs,
        Wt + 2 * (size_t)UNIT_W, bg1, bg1 + UU, st_h, nullptr,
        rst_h, u_h, nullptr, M);

    // gru2: c = tanh(.); out = u*st + (1-u)*c
    gemm16_k<2, 1><<<dim3(mb, 1), 256, 0, stream>>>(rst_h, inputs,
        Wt + 4 * (size_t)UNIT_W, bg2, nullptr, st_h, u_h,
        nullptr, nullptr, out, M);
}

// Round 5
// 260.768 us; speedup vs baseline: 4.9265x; 1.2377x over previous
//
#include <hip/hip_runtime.h>
#include <math.h>

#define NN 307
#define UU 100
#define DD 3
#define UP 104          // padded f16 activation row stride (208 B, 16B-aligned)
#define UNIT_W 14336    // f16 elements per packed weight unit (4*7*64*8 = 112x128)
#define SC_STRIDE 4608  // per-sample score stride (>= E+NN)

typedef _Float16 f16;
typedef f16  f16x2 __attribute__((ext_vector_type(2)));
typedef f16  f16x4 __attribute__((ext_vector_type(4)));
typedef f16  f16x8 __attribute__((ext_vector_type(8)));
typedef float f32x4 __attribute__((ext_vector_type(4)));

// ---------------------------------------------------------------------------
// Pack weights to f16 in MFMA *fragment order*:
//   Wp[u][((s*7 + j)*64 + l)*8 + e] = Wsrc[k][col],
//   col = j*16 + (l&15), k = (s*4 + (l>>4))*8 + e.
// A wave's B-fragment load for (s,j) is then 64 lanes x 16B = 1KB contiguous.
// GRU k-rows permuted to [big(100) | inputs(3)]:
// unit 0: Wl, 1: Wr, 2: Wg1[:, :100], 3: Wg1[:, 100:], 4: Wg2.
// ---------------------------------------------------------------------------
__global__ __launch_bounds__(256)
void pack_w_k(const float* __restrict__ Wl, const float* __restrict__ Wr,
              const float* __restrict__ Wg1, const float* __restrict__ Wg2,
              f16* __restrict__ Wp)
{
    const int total = 5 * UNIT_W;
    for (int idx = blockIdx.x * 256 + threadIdx.x; idx < total; idx += gridDim.x * 256) {
        const int u   = idx / UNIT_W;
        const int rem = idx - u * UNIT_W;
        const int e   = rem & 7;
        const int l   = (rem >> 3) & 63;
        const int sj  = rem >> 9;          // 0..27
        const int s   = sj / 7, j = sj - 7 * s;
        const int col = j * 16 + (l & 15);
        const int k   = (s * 4 + (l >> 4)) * 8 + e;
        float v = 0.f;
        if (col < UU && k < UU + DD) {
            if (u == 0)      v = Wl[k * UU + col];
            else if (u == 1) v = Wr[k * UU + col];
            else {
                const int kk = (k < UU) ? (k + DD) : (k - UU);
                if (u == 2)      v = Wg1[kk * (2 * UU) + col];
                else if (u == 3) v = Wg1[kk * (2 * UU) + UU + col];
                else             v = Wg2[kk * UU + col];
            }
        }
        Wp[idx] = (f16)v;
    }
}

// ---------------------------------------------------------------------------
// CSR build, parallel + deterministic (order-preserving).
// ---------------------------------------------------------------------------
__global__ __launch_bounds__(64)
void csr_count_k(const int* __restrict__ dst, int E, int* offs)
{
    const int d = blockIdx.x;
    const int lane = threadIdx.x;
    const int Etot = E + NN;
    int c = 0;
    for (int base = 0; base < Etot; base += 64) {
        const int e = base + lane;
        if (e < Etot) {
            const int de = (e < E) ? dst[e] : (e - E);
            c += (de == d) ? 1 : 0;
        }
    }
    #pragma unroll
    for (int m = 1; m < 64; m <<= 1) c += __shfl_xor(c, m, 64);
    if (lane == 0) {
        offs[d + 1] = c;
        if (d == 0) offs[0] = 0;
    }
}

__global__ void csr_scan_k(int* offs)
{
    if (threadIdx.x == 0) {
        int acc = 0;
        for (int i = 1; i <= NN; ++i) { acc += offs[i]; offs[i] = acc; }
    }
}

__global__ __launch_bounds__(64)
void csr_fill_k(const int* __restrict__ src, const int* __restrict__ dst,
                int E, const int* __restrict__ offs,
                int* eidx, int* ddst)
{
    const int d = blockIdx.x;
    const int lane = threadIdx.x;
    const int Etot = E + NN;
    int w = offs[d];
    for (int base = 0; base < Etot; base += 64) {
        const int e = base + lane;
        bool match = false;
        int se = 0;
        if (e < Etot) {
            const int de = (e < E) ? dst[e] : (e - E);
            se           = (e < E) ? src[e] : (e - E);
            match = (de == d);
        }
        const unsigned long long mask = __ballot(match);
        if (match) {
            const int pos = w + __popcll(mask & ((1ULL << lane) - 1ULL));
            eidx[pos] = se;
            ddst[pos] = d;
        }
        w += __popcll(mask);
    }
}

// ---------------------------------------------------------------------------
// GAT phase A: one thread per (b, edge); full 100-d dot, f16x8 loads.
// ---------------------------------------------------------------------------
__global__ __launch_bounds__(256)
void score_k(const f16* __restrict__ xl, const f16* __restrict__ xr,
             const int* __restrict__ eidx, const int* __restrict__ ddst,
             const float* __restrict__ att, int Etot, float* __restrict__ scores)
{
    const int b = blockIdx.y;
    const int i = blockIdx.x * 256 + threadIdx.x;
    if (i >= Etot) return;
    const int s = eidx[i];
    const int d = ddst[i];
    const f16* xls = xl + ((size_t)b * NN + s) * UP;
    const f16* xrd = xr + ((size_t)b * NN + d) * UP;
    float p = 0.f;
    #pragma unroll
    for (int u = 0; u < 96; u += 8) {
        const f16x8 a = *(const f16x8*)(xls + u);
        const f16x8 r = *(const f16x8*)(xrd + u);
        #pragma unroll
        for (int j = 0; j < 8; ++j) {
            float v = (float)a[j] + (float)r[j];
            v = v > 0.f ? v : 0.2f * v;
            p += v * att[u + j];
        }
    }
    {
        const f16x4 a = *(const f16x4*)(xls + 96);
        const f16x4 r = *(const f16x4*)(xrd + 96);
        #pragma unroll
        for (int j = 0; j < 4; ++j) {
            float v = (float)a[j] + (float)r[j];
            v = v > 0.f ? v : 0.2f * v;
            p += v * att[96 + j];
        }
    }
    scores[(size_t)b * SC_STRIDE + i] = p;
}

// ---------------------------------------------------------------------------
// GAT phase B: one wave per (b, d). Chunk-level online softmax; ex + eidx in
// LDS (broadcast); lanes 0..49 own feature pair (2l,2l+1) -> one f16x2 load
// per edge, x4 unroll. Writes st (f16, UP-stride) over the xr buffer.
// ---------------------------------------------------------------------------
__global__ __launch_bounds__(256)
void gatagg_k(const f16* __restrict__ xl, const float* __restrict__ scores,
              const int* __restrict__ offs, const int* __restrict__ eidx,
              const float* __restrict__ gb, const float* __restrict__ bgc,
              f16* __restrict__ stout)
{
    __shared__ float al[4][64];
    __shared__ int   sl[4][64];
    const int b    = blockIdx.x;
    const int wv   = threadIdx.x >> 6;
    const int wid  = blockIdx.y * 4 + wv;   // 0..31
    const int lane = threadIdx.x & 63;
    const bool act = (lane < 50);
    const int f0 = 2 * lane;
    float bs0 = 0.f, bs1 = 0.f;
    if (act) { bs0 = gb[f0] + bgc[f0]; bs1 = gb[f0 + 1] + bgc[f0 + 1]; }
    const f16* xlb = xl + (size_t)b * NN * UP;
    const float* scb = scores + (size_t)b * SC_STRIDE;
    f16* stb = stout + (size_t)b * NN * UP;

    for (int d = wid; d < NN; d += 32) {
        const int e0 = offs[d], e1 = offs[d + 1];
        float mx = -1e30f, dn = 0.f, a0 = 0.f, a1 = 0.f;
        for (int c0 = e0; c0 < e1; c0 += 64) {
            const int n = min(64, e1 - c0);
            const float sc = (lane < n) ? scb[c0 + lane] : -1e30f;
            const int  se  = (lane < n) ? eidx[c0 + lane] : 0;
            float cm = sc;
            #pragma unroll
            for (int m = 1; m < 64; m <<= 1) cm = fmaxf(cm, __shfl_xor(cm, m, 64));
            const float nm = fmaxf(mx, cm);
            const float rs = __expf(mx - nm);
            const float ex = (lane < n) ? __expf(sc - nm) : 0.f;
            float cs = ex;
            #pragma unroll
            for (int m = 1; m < 64; m <<= 1) cs += __shfl_xor(cs, m, 64);
            dn = dn * rs + cs;
            a0 *= rs; a1 *= rs;
            al[wv][lane] = ex;
            sl[wv][lane] = se;
            int i = 0;
            for (; i + 4 <= n; i += 4) {
                const float w0 = al[wv][i];     const int s0 = sl[wv][i];
                const float w1 = al[wv][i + 1]; const int s1 = sl[wv][i + 1];
                const float w2 = al[wv][i + 2]; const int s2 = sl[wv][i + 2];
                const float w3 = al[wv][i + 3]; const int s3 = sl[wv][i + 3];
                if (act) {
                    const f16x2 m0 = *(const f16x2*)(xlb + (size_t)s0 * UP + f0);
                    const f16x2 m1 = *(const f16x2*)(xlb + (size_t)s1 * UP + f0);
                    const f16x2 m2 = *(const f16x2*)(xlb + (size_t)s2 * UP + f0);
                    const f16x2 m3 = *(const f16x2*)(xlb + (size_t)s3 * UP + f0);
                    a0 += w0 * (float)m0[0] + w1 * (float)m1[0]
                        + w2 * (float)m2[0] + w3 * (float)m3[0];
                    a1 += w0 * (float)m0[1] + w1 * (float)m1[1]
                        + w2 * (float)m2[1] + w3 * (float)m3[1];
                }
            }
            for (; i < n; ++i) {
                const float w0 = al[wv][i]; const int s0 = sl[wv][i];
                if (act) {
                    const f16x2 m0 = *(const f16x2*)(xlb + (size_t)s0 * UP + f0);
                    a0 += w0 * (float)m0[0];
                    a1 += w0 * (float)m0[1];
                }
            }
            mx = nm;
        }
        if (act) {
            const float inv = 1.f / dn;
            f16x2 o;
            o[0] = (f16)(a0 * inv + bs0);
            o[1] = (f16)(a1 * inv + bs1);
            *(f16x2*)(stb + (size_t)d * UP + f0) = o;
        }
    }
}

// ---------------------------------------------------------------------------
// LDS-free register MFMA GEMM. Each wave owns 32 rows (2x 16-row tiles).
// A fragments loaded directly from global (each element read exactly once);
// B fragments from fragment-order-packed Wp (1KB coalesced, L1/L2-resident).
// No __shared__, no barriers -> occupancy is VGPR-bound (4 waves/SIMD).
// AF16: A is f16 UP-stride (else f32 UU-stride, i.e. `state`).
// MODE 0: y=0 -> outA = acc (xl); y=1 -> outB = acc (xr)
// MODE 1: y=0 -> outA = sigmoid(acc+biasA)*st ; y=1 -> outB = sigmoid(acc+biasB)
// MODE 2: c = tanh(acc+biasA); outF = u*st + (1-u)*c  (f32, d_out)
// ---------------------------------------------------------------------------
template<int MODE, int AF16>
__global__ __launch_bounds__(256, 4)
void gemm_reg_k(const void* __restrict__ bigv, const float* __restrict__ inp,
                const f16* __restrict__ Wp,
                const float* __restrict__ biasA, const float* __restrict__ biasB,
                const f16* __restrict__ st, const f16* __restrict__ uarr,
                f16* __restrict__ outA, f16* __restrict__ outB,
                float* __restrict__ outF, int M)
{
    const int tid = threadIdx.x;
    const int w   = tid >> 6;
    const int l   = tid & 63;
    const int lr  = l & 15;
    const int lk  = l >> 4;
    const int rb  = blockIdx.x * 128 + w * 32;
    const int y   = blockIdx.y;
    const f16* Wu = Wp + (size_t)y * UNIT_W;

    int rowA[2];
    #pragma unroll
    for (int t = 0; t < 2; ++t) {
        int row = rb + t * 16 + lr;
        rowA[t] = (row < M) ? row : (M - 1);
    }

    f32x4 acc[2][7];
    #pragma unroll
    for (int t = 0; t < 2; ++t)
        #pragma unroll
        for (int j = 0; j < 7; ++j) acc[t][j] = (f32x4)0.f;

    // ---- s = 0..2 : plain fragment loads (kb = s*4+lk in 0..11) ----
    #pragma unroll
    for (int s = 0; s < 3; ++s) {
        const int kb = s * 4 + lk;
        f16x8 af[2];
        #pragma unroll
        for (int t = 0; t < 2; ++t) {
            if (AF16) {
                const f16* bh = (const f16*)bigv + (size_t)rowA[t] * UP;
                af[t] = *(const f16x8*)(bh + kb * 8);
            } else {
                const float* bf = (const float*)bigv + (size_t)rowA[t] * UU;
                const float4 x0 = *(const float4*)(bf + kb * 8);
                const float4 x1 = *(const float4*)(bf + kb * 8 + 4);
                f16x8 v;
                v[0]=(f16)x0.x; v[1]=(f16)x0.y; v[2]=(f16)x0.z; v[3]=(f16)x0.w;
                v[4]=(f16)x1.x; v[5]=(f16)x1.y; v[6]=(f16)x1.z; v[7]=(f16)x1.w;
                af[t] = v;
            }
        }
        #pragma unroll
        for (int j = 0; j < 7; ++j) {
            const f16x8 bv = *(const f16x8*)(Wu + (((s * 7 + j) * 64 + l) << 3));
            #pragma unroll
            for (int t = 0; t < 2; ++t)
                acc[t][j] = __builtin_amdgcn_mfma_f32_16x16x32_f16(af[t], bv, acc[t][j], 0, 0, 0);
        }
    }

    // ---- s = 3 : kb = 12 + lk; only lk==0 carries data (k 96..99 + inputs) ----
    {
        f16x8 af[2];
        #pragma unroll
        for (int t = 0; t < 2; ++t) {
            f16x8 v = (f16x8)(f16)0.f;
            if (lk == 0) {
                const int row = rowA[t];
                if (AF16) {
                    const f16* bh = (const f16*)bigv + (size_t)row * UP;
                    v = *(const f16x8*)(bh + 96);   // 96..99 real, 100..103 pad
                } else {
                    const float* bf = (const float*)bigv + (size_t)row * UU;
                    const float4 x0 = *(const float4*)(bf + 96);
                    v[0]=(f16)x0.x; v[1]=(f16)x0.y; v[2]=(f16)x0.z; v[3]=(f16)x0.w;
                }
                v[4] = (f16)inp[(size_t)row * DD + 0];
                v[5] = (f16)inp[(size_t)row * DD + 1];
                v[6] = (f16)inp[(size_t)row * DD + 2];
                v[7] = (f16)0.f;
            }
            af[t] = v;
        }
        #pragma unroll
        for (int j = 0; j < 7; ++j) {
            const f16x8 bv = *(const f16x8*)(Wu + (((3 * 7 + j) * 64 + l) << 3));
            #pragma unroll
            for (int t = 0; t < 2; ++t)
                acc[t][j] = __builtin_amdgcn_mfma_f32_16x16x32_f16(af[t], bv, acc[t][j], 0, 0, 0);
        }
    }

    // ---- epilogue: C layout col = lane&15, row = (lane>>4)*4 + reg ----
    #pragma unroll
    for (int t = 0; t < 2; ++t) {
        #pragma unroll
        for (int j = 0; j < 7; ++j) {
            const int col = j * 16 + lr;
            if (col >= UU) continue;
            const int row0 = rb + t * 16 + lk * 4;
            #pragma unroll
            for (int r = 0; r < 4; ++r) {
                const int row = row0 + r;
                if (row >= M) continue;
                const float a = acc[t][j][r];
                const size_t oh = (size_t)row * UP + col;
                if (MODE == 0) {
                    (y ? outB : outA)[oh] = (f16)a;
                } else if (MODE == 1) {
                    if (y == 0) {
                        const float sg = 1.f / (1.f + __expf(-(a + biasA[col])));
                        outA[oh] = (f16)(sg * (float)st[oh]);
                    } else {
                        outB[oh] = (f16)(1.f / (1.f + __expf(-(a + biasB[col]))));
                    }
                } else {
                    const float c = tanhf(a + biasA[col]);
                    const float u = (float)uarr[oh];
                    const float s2 = (float)st[oh];
                    outF[(size_t)row * UU + col] = u * s2 + (1.f - u) * c;
                }
            }
        }
    }
}

// ---------------------------------------------------------------------------
extern "C" void kernel_launch(void* const* d_in, const int* in_sizes, int n_in,
                              void* d_out, int out_size, void* d_ws, size_t ws_size,
                              hipStream_t stream)
{
    const float* inputs   = (const float*)d_in[0];
    const float* state    = (const float*)d_in[1];
    const int*   src      = (const int*)  d_in[2];
    const int*   dst      = (const int*)  d_in[3];
    const float* Wl       = (const float*)d_in[4];
    const float* Wr       = (const float*)d_in[5];
    const float* att      = (const float*)d_in[6];
    const float* gat_bias = (const float*)d_in[7];
    const float* bias_gc  = (const float*)d_in[8];
    const float* Wg1      = (const float*)d_in[9];
    const float* bg1      = (const float*)d_in[10];
    const float* Wg2      = (const float*)d_in[11];
    const float* bg2      = (const float*)d_in[12];

    const int E = in_sizes[2];
    const int B = in_sizes[1] / (NN * UU);
    const int M = B * NN;
    const int Etot = E + NN;

    char* ws = (char*)d_ws;
    const size_t SH = (size_t)M * UP * sizeof(f16);
    f16* xl_h = (f16*)ws;                             // later reused as r*st
    f16* xr_h = (f16*)(ws + SH);                      // later reused as st
    f16* u_h  = (f16*)(ws + 2 * SH);
    f16* Wp   = (f16*)(ws + 3 * SH);
    int* offs = (int*)(ws + 3 * SH + 5 * UNIT_W * sizeof(f16));
    int* eidx = offs + (NN + 1);
    int* ddst = eidx + (Etot + 64);
    f16* st_h  = xr_h;                                // st overwrites xr
    f16* rst_h = xl_h;                                // r*st overwrites xl
    float* out = (float*)d_out;
    float* scores = (float*)d_out;                    // dead before out write

    const int mb = (M + 127) / 128;

    pack_w_k<<<56, 256, 0, stream>>>(Wl, Wr, Wg1, Wg2, Wp);
    csr_count_k<<<NN, 64, 0, stream>>>(dst, E, offs);
    csr_scan_k<<<1, 64, 0, stream>>>(offs);
    csr_fill_k<<<NN, 64, 0, stream>>>(src, dst, E, offs, eidx, ddst);

    // xl = [state|inputs] @ Wl ; xr = [state|inputs] @ Wr   (f16 out)
    gemm_reg_k<0, 0><<<dim3(mb, 2), 256, 0, stream>>>(state, inputs, Wp,
        nullptr, nullptr, nullptr, nullptr, xl_h, xr_h, nullptr, M);

    // GAT scores (edge-parallel) then softmax+aggregate -> st
    score_k<<<dim3((Etot + 255) / 256, B), 256, 0, stream>>>(xl_h, xr_h, eidx,
        ddst, att, Etot, scores);
    gatagg_k<<<dim3(B, 8), 256, 0, stream>>>(xl_h, scores, offs, eidx,
        gat_bias, bias_gc, st_h);

    // gru1: y=0 -> rst = sigmoid(.)*st ; y=1 -> u = sigmoid(.)
    gemm_reg_k<1, 1><<<dim3(mb, 2), 256, 0, stream>>>(st_h, inputs,
        Wp + 2 * (size_t)UNIT_W, bg1, bg1 + UU, st_h, nullptr,
        rst_h, u_h, nullptr, M);

    // gru2: c = tanh(.); out = u*st + (1-u)*c
    gemm_reg_k<2, 1><<<dim3(mb, 1), 256, 0, stream>>>(rst_h, inputs,
        Wp + 4 * (size_t)UNIT_W, bg2, nullptr, st_h, u_h,
        nullptr, nullptr, out, M);
}

// Round 6
// 256.084 us; speedup vs baseline: 5.0166x; 1.0183x over previous
//
#include <hip/hip_runtime.h>
#include <math.h>

#define NN 307
#define UU 100
#define DD 3
#define UP 104          // padded f16 activation row stride (208 B, 16B-aligned)
#define UNIT_W 14336    // f16 elements per packed weight unit (4*7*64*8 = 112x128)
#define SC_CAP 4608     // LDS score capacity (>= E+NN = 4403)

typedef _Float16 f16;
typedef f16  f16x2 __attribute__((ext_vector_type(2)));
typedef f16  f16x4 __attribute__((ext_vector_type(4)));
typedef f16  f16x8 __attribute__((ext_vector_type(8)));
typedef float f32x4 __attribute__((ext_vector_type(4)));

// ---------------------------------------------------------------------------
// Pack weights to f16 in MFMA *fragment order*:
//   Wp[u][((s*7 + j)*64 + l)*8 + e] = Wsrc[k][col],
//   col = j*16 + (l&15), k = (s*4 + (l>>4))*8 + e.
// GRU k-rows permuted to [big(100) | inputs(3)].
// unit 0: Wl, 1: Wr, 2: Wg1[:, :100], 3: Wg1[:, 100:], 4: Wg2.
// ---------------------------------------------------------------------------
__global__ __launch_bounds__(256)
void pack_w_k(const float* __restrict__ Wl, const float* __restrict__ Wr,
              const float* __restrict__ Wg1, const float* __restrict__ Wg2,
              f16* __restrict__ Wp)
{
    const int total = 5 * UNIT_W;
    for (int idx = blockIdx.x * 256 + threadIdx.x; idx < total; idx += gridDim.x * 256) {
        const int u   = idx / UNIT_W;
        const int rem = idx - u * UNIT_W;
        const int e   = rem & 7;
        const int l   = (rem >> 3) & 63;
        const int sj  = rem >> 9;          // 0..27
        const int s   = sj / 7, j = sj - 7 * s;
        const int col = j * 16 + (l & 15);
        const int k   = (s * 4 + (l >> 4)) * 8 + e;
        float v = 0.f;
        if (col < UU && k < UU + DD) {
            if (u == 0)      v = Wl[k * UU + col];
            else if (u == 1) v = Wr[k * UU + col];
            else {
                const int kk = (k < UU) ? (k + DD) : (k - UU);
                if (u == 2)      v = Wg1[kk * (2 * UU) + col];
                else if (u == 3) v = Wg1[kk * (2 * UU) + UU + col];
                else             v = Wg2[kk * UU + col];
            }
        }
        Wp[idx] = (f16)v;
    }
}

// ---------------------------------------------------------------------------
// CSR build, parallel + deterministic (order-preserving).
// ---------------------------------------------------------------------------
__global__ __launch_bounds__(64)
void csr_count_k(const int* __restrict__ dst, int E, int* offs)
{
    const int d = blockIdx.x;
    const int lane = threadIdx.x;
    const int Etot = E + NN;
    int c = 0;
    for (int base = 0; base < Etot; base += 64) {
        const int e = base + lane;
        if (e < Etot) {
            const int de = (e < E) ? dst[e] : (e - E);
            c += (de == d) ? 1 : 0;
        }
    }
    #pragma unroll
    for (int m = 1; m < 64; m <<= 1) c += __shfl_xor(c, m, 64);
    if (lane == 0) {
        offs[d + 1] = c;
        if (d == 0) offs[0] = 0;
    }
}

__global__ void csr_scan_k(int* offs)
{
    if (threadIdx.x == 0) {
        int acc = 0;
        for (int i = 1; i <= NN; ++i) { acc += offs[i]; offs[i] = acc; }
    }
}

__global__ __launch_bounds__(64)
void csr_fill_k(const int* __restrict__ src, const int* __restrict__ dst,
                int E, const int* __restrict__ offs,
                int* eidx, int* ddst)
{
    const int d = blockIdx.x;
    const int lane = threadIdx.x;
    const int Etot = E + NN;
    int w = offs[d];
    for (int base = 0; base < Etot; base += 64) {
        const int e = base + lane;
        bool match = false;
        int se = 0;
        if (e < Etot) {
            const int de = (e < E) ? dst[e] : (e - E);
            se           = (e < E) ? src[e] : (e - E);
            match = (de == d);
        }
        const unsigned long long mask = __ballot(match);
        if (match) {
            const int pos = w + __popcll(mask & ((1ULL << lane) - 1ULL));
            eidx[pos] = se;
            ddst[pos] = d;
        }
        w += __popcll(mask);
    }
}

// ---------------------------------------------------------------------------
// Fused GAT: one block per sample (B = 256 = #CUs), 512 threads.
// A) stage xl[b] (64 KB) into LDS, coalesced.
// B) scores: thread-per-edge (CSR order). xl[s] from LDS; xr[d] from global
//    (CSR d-locality -> coalesced L1 hits). Scores -> LDS.
// C) stats: thread-per-dst serial max/denom (deg~14), alpha written in-place.
// D) aggregate: 16-lane group per dst; 13 lanes x f16x8 cover the row; one
//    ds_read_b128 + alpha broadcast per edge; coalesced 208B st-row write.
// st (f16, UP-stride) overwrites xr; safe within block via barriers.
// ---------------------------------------------------------------------------
__global__ __launch_bounds__(512, 1)
void gat_fused_k(const f16* __restrict__ xl, const f16* __restrict__ xr,
                 const int* __restrict__ offs, const int* __restrict__ eidx,
                 const int* __restrict__ ddst,
                 const float* __restrict__ att, const float* __restrict__ gb,
                 const float* __restrict__ bgc, int Etot,
                 f16* __restrict__ stout)
{
    __shared__ f16   xl_s[NN * UP];    // 63856 B
    __shared__ float sc_s[SC_CAP];     // 18432 B

    const int b   = blockIdx.x;
    const int tid = threadIdx.x;
    const f16* xlb = xl + (size_t)b * NN * UP;
    const f16* xrb = xr + (size_t)b * NN * UP;
    f16* stb = stout + (size_t)b * NN * UP;

    // ---- A: stage xl ----
    for (int c = tid; c < NN * UP / 8; c += 512)
        *(f16x8*)&xl_s[c * 8] = *(const f16x8*)&xlb[c * 8];
    __syncthreads();

    // ---- B: scores ----
    for (int i = tid; i < Etot; i += 512) {
        const int s = eidx[i];
        const int d = ddst[i];
        const f16* xls = &xl_s[s * UP];
        const f16* xrd = xrb + (size_t)d * UP;
        float p = 0.f;
        #pragma unroll
        for (int u = 0; u < 96; u += 8) {
            const f16x8 a = *(const f16x8*)(xls + u);
            const f16x8 r = *(const f16x8*)(xrd + u);
            #pragma unroll
            for (int j = 0; j < 8; ++j) {
                float v = (float)a[j] + (float)r[j];
                v = v > 0.f ? v : 0.2f * v;
                p += v * att[u + j];
            }
        }
        {
            const f16x4 a = *(const f16x4*)(xls + 96);
            const f16x4 r = *(const f16x4*)(xrd + 96);
            #pragma unroll
            for (int j = 0; j < 4; ++j) {
                float v = (float)a[j] + (float)r[j];
                v = v > 0.f ? v : 0.2f * v;
                p += v * att[96 + j];
            }
        }
        sc_s[i] = p;
    }
    __syncthreads();

    // ---- C: per-dst softmax stats, alpha in-place ----
    if (tid < NN) {
        const int e0 = offs[tid], e1 = offs[tid + 1];
        float mx = -1e30f;
        for (int e = e0; e < e1; ++e) mx = fmaxf(mx, sc_s[e]);
        float dn = 0.f;
        for (int e = e0; e < e1; ++e) {
            const float ex = __expf(sc_s[e] - mx);
            sc_s[e] = ex;
            dn += ex;
        }
        const float inv = 1.f / dn;
        for (int e = e0; e < e1; ++e) sc_s[e] *= inv;
    }
    __syncthreads();

    // ---- D: aggregate. 16-lane group per dst ----
    const int w   = tid >> 6;     // wave 0..7
    const int grp = (tid >> 4) & 3;
    const int sub = tid & 15;     // feature chunk; sub<13 active
    const bool fa = (sub < 13);
    float bias_r[8];
    #pragma unroll
    for (int k = 0; k < 8; ++k) {
        const int f = sub * 8 + k;
        bias_r[k] = (fa && f < UU) ? (gb[f] + bgc[f]) : 0.f;
    }
    for (int d0 = w * 4; d0 < NN; d0 += 32) {
        const int d = d0 + grp;
        const bool da = (d < NN);
        const int e0 = da ? offs[d] : 0;
        const int e1 = da ? offs[d + 1] : 0;
        float acc[8] = {0.f, 0.f, 0.f, 0.f, 0.f, 0.f, 0.f, 0.f};
        for (int e = e0; e < e1; ++e) {
            const float alpha = sc_s[e];                 // group-uniform broadcast
            const int s = eidx[e];                       // group-uniform, L1-hot
            if (fa) {
                const f16x8 m = *(const f16x8*)&xl_s[s * UP + sub * 8];
                #pragma unroll
                for (int k = 0; k < 8; ++k) acc[k] += alpha * (float)m[k];
            }
        }
        if (da && fa) {
            f16x8 o;
            #pragma unroll
            for (int k = 0; k < 8; ++k) o[k] = (f16)(acc[k] + bias_r[k]);
            *(f16x8*)(stb + (size_t)d * UP + sub * 8) = o;
        }
    }
}

// ---------------------------------------------------------------------------
// LDS-free register MFMA GEMM (unchanged from round 5).
// ---------------------------------------------------------------------------
template<int MODE, int AF16>
__global__ __launch_bounds__(256, 4)
void gemm_reg_k(const void* __restrict__ bigv, const float* __restrict__ inp,
                const f16* __restrict__ Wp,
                const float* __restrict__ biasA, const float* __restrict__ biasB,
                const f16* __restrict__ st, const f16* __restrict__ uarr,
                f16* __restrict__ outA, f16* __restrict__ outB,
                float* __restrict__ outF, int M)
{
    const int tid = threadIdx.x;
    const int w   = tid >> 6;
    const int l   = tid & 63;
    const int lr  = l & 15;
    const int lk  = l >> 4;
    const int rb  = blockIdx.x * 128 + w * 32;
    const int y   = blockIdx.y;
    const f16* Wu = Wp + (size_t)y * UNIT_W;

    int rowA[2];
    #pragma unroll
    for (int t = 0; t < 2; ++t) {
        int row = rb + t * 16 + lr;
        rowA[t] = (row < M) ? row : (M - 1);
    }

    f32x4 acc[2][7];
    #pragma unroll
    for (int t = 0; t < 2; ++t)
        #pragma unroll
        for (int j = 0; j < 7; ++j) acc[t][j] = (f32x4)0.f;

    #pragma unroll
    for (int s = 0; s < 3; ++s) {
        const int kb = s * 4 + lk;
        f16x8 af[2];
        #pragma unroll
        for (int t = 0; t < 2; ++t) {
            if (AF16) {
                const f16* bh = (const f16*)bigv + (size_t)rowA[t] * UP;
                af[t] = *(const f16x8*)(bh + kb * 8);
            } else {
                const float* bf = (const float*)bigv + (size_t)rowA[t] * UU;
                const float4 x0 = *(const float4*)(bf + kb * 8);
                const float4 x1 = *(const float4*)(bf + kb * 8 + 4);
                f16x8 v;
                v[0]=(f16)x0.x; v[1]=(f16)x0.y; v[2]=(f16)x0.z; v[3]=(f16)x0.w;
                v[4]=(f16)x1.x; v[5]=(f16)x1.y; v[6]=(f16)x1.z; v[7]=(f16)x1.w;
                af[t] = v;
            }
        }
        #pragma unroll
        for (int j = 0; j < 7; ++j) {
            const f16x8 bv = *(const f16x8*)(Wu + (((s * 7 + j) * 64 + l) << 3));
            #pragma unroll
            for (int t = 0; t < 2; ++t)
                acc[t][j] = __builtin_amdgcn_mfma_f32_16x16x32_f16(af[t], bv, acc[t][j], 0, 0, 0);
        }
    }

    {
        f16x8 af[2];
        #pragma unroll
        for (int t = 0; t < 2; ++t) {
            f16x8 v = (f16x8)(f16)0.f;
            if (lk == 0) {
                const int row = rowA[t];
                if (AF16) {
                    const f16* bh = (const f16*)bigv + (size_t)row * UP;
                    v = *(const f16x8*)(bh + 96);
                } else {
                    const float* bf = (const float*)bigv + (size_t)row * UU;
                    const float4 x0 = *(const float4*)(bf + 96);
                    v[0]=(f16)x0.x; v[1]=(f16)x0.y; v[2]=(f16)x0.z; v[3]=(f16)x0.w;
                }
                v[4] = (f16)inp[(size_t)row * DD + 0];
                v[5] = (f16)inp[(size_t)row * DD + 1];
                v[6] = (f16)inp[(size_t)row * DD + 2];
                v[7] = (f16)0.f;
            }
            af[t] = v;
        }
        #pragma unroll
        for (int j = 0; j < 7; ++j) {
            const f16x8 bv = *(const f16x8*)(Wu + (((3 * 7 + j) * 64 + l) << 3));
            #pragma unroll
            for (int t = 0; t < 2; ++t)
                acc[t][j] = __builtin_amdgcn_mfma_f32_16x16x32_f16(af[t], bv, acc[t][j], 0, 0, 0);
        }
    }

    #pragma unroll
    for (int t = 0; t < 2; ++t) {
        #pragma unroll
        for (int j = 0; j < 7; ++j) {
            const int col = j * 16 + lr;
            if (col >= UU) continue;
            const int row0 = rb + t * 16 + lk * 4;
            #pragma unroll
            for (int r = 0; r < 4; ++r) {
                const int row = row0 + r;
                if (row >= M) continue;
                const float a = acc[t][j][r];
                const size_t oh = (size_t)row * UP + col;
                if (MODE == 0) {
                    (y ? outB : outA)[oh] = (f16)a;
                } else if (MODE == 1) {
                    if (y == 0) {
                        const float sg = 1.f / (1.f + __expf(-(a + biasA[col])));
                        outA[oh] = (f16)(sg * (float)st[oh]);
                    } else {
                        outB[oh] = (f16)(1.f / (1.f + __expf(-(a + biasB[col]))));
                    }
                } else {
                    const float c = tanhf(a + biasA[col]);
                    const float u = (float)uarr[oh];
                    const float s2 = (float)st[oh];
                    outF[(size_t)row * UU + col] = u * s2 + (1.f - u) * c;
                }
            }
        }
    }
}

// ---------------------------------------------------------------------------
extern "C" void kernel_launch(void* const* d_in, const int* in_sizes, int n_in,
                              void* d_out, int out_size, void* d_ws, size_t ws_size,
                              hipStream_t stream)
{
    const float* inputs   = (const float*)d_in[0];
    const float* state    = (const float*)d_in[1];
    const int*   src      = (const int*)  d_in[2];
    const int*   dst      = (const int*)  d_in[3];
    const float* Wl       = (const float*)d_in[4];
    const float* Wr       = (const float*)d_in[5];
    const float* att      = (const float*)d_in[6];
    const float* gat_bias = (const float*)d_in[7];
    const float* bias_gc  = (const float*)d_in[8];
    const float* Wg1      = (const float*)d_in[9];
    const float* bg1      = (const float*)d_in[10];
    const float* Wg2      = (const float*)d_in[11];
    const float* bg2      = (const float*)d_in[12];

    const int E = in_sizes[2];
    const int B = in_sizes[1] / (NN * UU);
    const int M = B * NN;
    const int Etot = E + NN;

    char* ws = (char*)d_ws;
    const size_t SH = (size_t)M * UP * sizeof(f16);
    f16* xl_h = (f16*)ws;                             // later reused as r*st
    f16* xr_h = (f16*)(ws + SH);                      // later reused as st
    f16* u_h  = (f16*)(ws + 2 * SH);
    f16* Wp   = (f16*)(ws + 3 * SH);
    int* offs = (int*)(ws + 3 * SH + 5 * UNIT_W * sizeof(f16));
    int* eidx = offs + (NN + 1);
    int* ddst = eidx + (Etot + 64);
    f16* st_h  = xr_h;                                // st overwrites xr
    f16* rst_h = xl_h;                                // r*st overwrites xl
    float* out = (float*)d_out;

    const int mb = (M + 127) / 128;

    pack_w_k<<<56, 256, 0, stream>>>(Wl, Wr, Wg1, Wg2, Wp);
    csr_count_k<<<NN, 64, 0, stream>>>(dst, E, offs);
    csr_scan_k<<<1, 64, 0, stream>>>(offs);
    csr_fill_k<<<NN, 64, 0, stream>>>(src, dst, E, offs, eidx, ddst);

    // xl = [state|inputs] @ Wl ; xr = [state|inputs] @ Wr   (f16 out)
    gemm_reg_k<0, 0><<<dim3(mb, 2), 256, 0, stream>>>(state, inputs, Wp,
        nullptr, nullptr, nullptr, nullptr, xl_h, xr_h, nullptr, M);

    // Fused GAT: scores + softmax + aggregate -> st (over xr buffer)
    gat_fused_k<<<B, 512, 0, stream>>>(xl_h, xr_h, offs, eidx, ddst,
        att, gat_bias, bias_gc, Etot, st_h);

    // gru1: y=0 -> rst = sigmoid(.)*st ; y=1 -> u = sigmoid(.)
    gemm_reg_k<1, 1><<<dim3(mb, 2), 256, 0, stream>>>(st_h, inputs,
        Wp + 2 * (size_t)UNIT_W, bg1, bg1 + UU, st_h, nullptr,
        rst_h, u_h, nullptr, M);

    // gru2: c = tanh(.); out = u*st + (1-u)*c
    gemm_reg_k<2, 1><<<dim3(mb, 1), 256, 0, stream>>>(rst_h, inputs,
        Wp + 4 * (size_t)UNIT_W, bg2, nullptr, st_h, u_h,
        nullptr, nullptr, out, M);
}

// Round 7
// 177.838 us; speedup vs baseline: 7.2238x; 1.4400x over previous
//
#include <hip/hip_runtime.h>
#include <math.h>

#define NN 307
#define UU 100
#define DD 3
#define UP 104          // padded f16 activation row stride (208 B, 16B-aligned)
#define UNIT_W 14336    // f16 elements per packed weight unit (4*7*64*8 = 112x128)
#define SC_CAP 4608     // LDS score capacity (>= E+NN = 4403)

typedef _Float16 f16;
typedef f16  f16x2 __attribute__((ext_vector_type(2)));
typedef f16  f16x4 __attribute__((ext_vector_type(4)));
typedef f16  f16x8 __attribute__((ext_vector_type(8)));
typedef float f32x4 __attribute__((ext_vector_type(4)));

// ---------------------------------------------------------------------------
// Pack weights to f16 in MFMA *fragment order*:
//   Wp[u][((s*7 + j)*64 + l)*8 + e] = Wsrc[k][col],
//   col = j*16 + (l&15), k = (s*4 + (l>>4))*8 + e.
// GRU k-rows permuted to [big(100) | inputs(3)].
// unit 0: Wl, 1: Wr, 2: Wg1[:, :100], 3: Wg1[:, 100:], 4: Wg2.
// ---------------------------------------------------------------------------
__global__ __launch_bounds__(256)
void pack_w_k(const float* __restrict__ Wl, const float* __restrict__ Wr,
              const float* __restrict__ Wg1, const float* __restrict__ Wg2,
              f16* __restrict__ Wp)
{
    const int total = 5 * UNIT_W;
    for (int idx = blockIdx.x * 256 + threadIdx.x; idx < total; idx += gridDim.x * 256) {
        const int u   = idx / UNIT_W;
        const int rem = idx - u * UNIT_W;
        const int e   = rem & 7;
        const int l   = (rem >> 3) & 63;
        const int sj  = rem >> 9;          // 0..27
        const int s   = sj / 7, j = sj - 7 * s;
        const int col = j * 16 + (l & 15);
        const int k   = (s * 4 + (l >> 4)) * 8 + e;
        float v = 0.f;
        if (col < UU && k < UU + DD) {
            if (u == 0)      v = Wl[k * UU + col];
            else if (u == 1) v = Wr[k * UU + col];
            else {
                const int kk = (k < UU) ? (k + DD) : (k - UU);
                if (u == 2)      v = Wg1[kk * (2 * UU) + col];
                else if (u == 3) v = Wg1[kk * (2 * UU) + UU + col];
                else             v = Wg2[kk * UU + col];
            }
        }
        Wp[idx] = (f16)v;
    }
}

// ---------------------------------------------------------------------------
// CSR build, parallel + deterministic (order-preserving).
// ---------------------------------------------------------------------------
__global__ __launch_bounds__(64)
void csr_count_k(const int* __restrict__ dst, int E, int* offs)
{
    const int d = blockIdx.x;
    const int lane = threadIdx.x;
    const int Etot = E + NN;
    int c = 0;
    for (int base = 0; base < Etot; base += 64) {
        const int e = base + lane;
        if (e < Etot) {
            const int de = (e < E) ? dst[e] : (e - E);
            c += (de == d) ? 1 : 0;
        }
    }
    #pragma unroll
    for (int m = 1; m < 64; m <<= 1) c += __shfl_xor(c, m, 64);
    if (lane == 0) {
        offs[d + 1] = c;
        if (d == 0) offs[0] = 0;
    }
}

__global__ void csr_scan_k(int* offs)
{
    if (threadIdx.x == 0) {
        int acc = 0;
        for (int i = 1; i <= NN; ++i) { acc += offs[i]; offs[i] = acc; }
    }
}

__global__ __launch_bounds__(64)
void csr_fill_k(const int* __restrict__ src, const int* __restrict__ dst,
                int E, const int* __restrict__ offs,
                int* eidx, int* ddst)
{
    const int d = blockIdx.x;
    const int lane = threadIdx.x;
    const int Etot = E + NN;
    int w = offs[d];
    for (int base = 0; base < Etot; base += 64) {
        const int e = base + lane;
        bool match = false;
        int se = 0;
        if (e < Etot) {
            const int de = (e < E) ? dst[e] : (e - E);
            se           = (e < E) ? src[e] : (e - E);
            match = (de == d);
        }
        const unsigned long long mask = __ballot(match);
        if (match) {
            const int pos = w + __popcll(mask & ((1ULL << lane) - 1ULL));
            eidx[pos] = se;
            ddst[pos] = d;
        }
        w += __popcll(mask);
    }
}

// ---------------------------------------------------------------------------
// Fused GAT: one block per sample, 1024 threads (16 waves/CU).
// A) stage xl[b] (64 KB) -> LDS.
// B) scores thread-per-edge: packed-f16 leaky + v_dot2_f32_f16, att hoisted
//    into 52 f16x2 regs (no per-edge reloads), 2 accumulators for dep chain.
// C) per-dst serial softmax stats (deg~14), alpha in-place in LDS.
// D) 16-lane group per dst aggregate, f16x8 rows from LDS.
// ---------------------------------------------------------------------------
__global__ __launch_bounds__(1024, 4)
void gat_fused_k(const f16* __restrict__ xl, const f16* __restrict__ xr,
                 const int* __restrict__ offs, const int* __restrict__ eidx,
                 const int* __restrict__ ddst,
                 const float* __restrict__ att, const float* __restrict__ gb,
                 const float* __restrict__ bgc, int Etot,
                 f16* __restrict__ stout)
{
    __shared__ f16   xl_s[NN * UP];    // 63856 B
    __shared__ float sc_s[SC_CAP];     // 18432 B

    const int b   = blockIdx.x;
    const int tid = threadIdx.x;
    const f16* xlb = xl + (size_t)b * NN * UP;
    const f16* xrb = xr + (size_t)b * NN * UP;
    f16* stb = stout + (size_t)b * NN * UP;

    // hoist att -> 52 f16x2 registers (zero-padded past col 100)
    f16x2 attr[52];
    #pragma unroll
    for (int i = 0; i < 52; ++i) {
        f16x2 v;
        v[0] = (2 * i     < UU) ? (f16)att[2 * i]     : (f16)0.f;
        v[1] = (2 * i + 1 < UU) ? (f16)att[2 * i + 1] : (f16)0.f;
        attr[i] = v;
    }

    // ---- A: stage xl ----
    for (int c = tid; c < NN * UP / 8; c += 1024)
        *(f16x8*)&xl_s[c * 8] = *(const f16x8*)&xlb[c * 8];
    __syncthreads();

    // ---- B: scores ----
    for (int i = tid; i < Etot; i += 1024) {
        const int s = eidx[i];
        const int d = ddst[i];
        const f16x8* a8 = (const f16x8*)&xl_s[s * UP];
        const f16x8* r8 = (const f16x8*)(xrb + (size_t)d * UP);
        float p0 = 0.f, p1 = 0.f;
        #pragma unroll
        for (int c = 0; c < 13; ++c) {
            const f16x8 x  = a8[c] + r8[c];
            const f16x8 xm = x * (f16)0.2f;
            const f16x8 y  = __builtin_elementwise_max(x, xm);   // leaky_relu
            const f16x2* y2 = (const f16x2*)&y;
#if __has_builtin(__builtin_amdgcn_fdot2)
            p0 = __builtin_amdgcn_fdot2(y2[0], attr[4 * c + 0], p0, false);
            p1 = __builtin_amdgcn_fdot2(y2[1], attr[4 * c + 1], p1, false);
            p0 = __builtin_amdgcn_fdot2(y2[2], attr[4 * c + 2], p0, false);
            p1 = __builtin_amdgcn_fdot2(y2[3], attr[4 * c + 3], p1, false);
#else
            #pragma unroll
            for (int q = 0; q < 4; ++q) {
                p0 += (float)y2[q][0] * (float)attr[4 * c + q][0];
                p1 += (float)y2[q][1] * (float)attr[4 * c + q][1];
            }
#endif
        }
        sc_s[i] = p0 + p1;
    }
    __syncthreads();

    // ---- C: per-dst softmax stats, alpha in-place ----
    if (tid < NN) {
        const int e0 = offs[tid], e1 = offs[tid + 1];
        float mx = -1e30f;
        for (int e = e0; e < e1; ++e) mx = fmaxf(mx, sc_s[e]);
        float dn = 0.f;
        for (int e = e0; e < e1; ++e) {
            const float ex = __expf(sc_s[e] - mx);
            sc_s[e] = ex;
            dn += ex;
        }
        const float inv = 1.f / dn;
        for (int e = e0; e < e1; ++e) sc_s[e] *= inv;
    }
    __syncthreads();

    // ---- D: aggregate. 16-lane group per dst ----
    const int w   = tid >> 6;     // wave 0..15
    const int grp = (tid >> 4) & 3;
    const int sub = tid & 15;     // feature chunk; sub<13 active
    const bool fa = (sub < 13);
    float bias_r[8];
    #pragma unroll
    for (int k = 0; k < 8; ++k) {
        const int f = sub * 8 + k;
        bias_r[k] = (fa && f < UU) ? (gb[f] + bgc[f]) : 0.f;
    }
    for (int d0 = w * 4; d0 < NN; d0 += 64) {
        const int d = d0 + grp;
        const bool da = (d < NN);
        const int e0 = da ? offs[d] : 0;
        const int e1 = da ? offs[d + 1] : 0;
        float acc[8] = {0.f, 0.f, 0.f, 0.f, 0.f, 0.f, 0.f, 0.f};
        for (int e = e0; e < e1; ++e) {
            const float alpha = sc_s[e];                 // group-uniform broadcast
            const int s = eidx[e];
            if (fa) {
                const f16x8 m = *(const f16x8*)&xl_s[s * UP + sub * 8];
                #pragma unroll
                for (int k = 0; k < 8; ++k) acc[k] += alpha * (float)m[k];
            }
        }
        if (da && fa) {
            f16x8 o;
            #pragma unroll
            for (int k = 0; k < 8; ++k) o[k] = (f16)(acc[k] + bias_r[k]);
            *(f16x8*)(stb + (size_t)d * UP + sub * 8) = o;
        }
    }
}

// ---------------------------------------------------------------------------
// MFMA helper: 4 K-steps x 7 col-tiles x 2 row-tiles against one weight unit.
// ---------------------------------------------------------------------------
__device__ __forceinline__ void mma_unit(const f16x8 (&af)[4][2],
                                         const f16* __restrict__ Wu,
                                         int l, f32x4 (&acc)[2][7])
{
    #pragma unroll
    for (int s = 0; s < 4; ++s)
        #pragma unroll
        for (int j = 0; j < 7; ++j) {
            const f16x8 bv = *(const f16x8*)(Wu + (((s * 7 + j) * 64 + l) << 3));
            acc[0][j] = __builtin_amdgcn_mfma_f32_16x16x32_f16(af[s][0], bv, acc[0][j], 0, 0, 0);
            acc[1][j] = __builtin_amdgcn_mfma_f32_16x16x32_f16(af[s][1], bv, acc[1][j], 0, 0, 0);
        }
}

__device__ __forceinline__ void acc_zero(f32x4 (&acc)[2][7])
{
    #pragma unroll
    for (int t = 0; t < 2; ++t)
        #pragma unroll
        for (int j = 0; j < 7; ++j) acc[t][j] = (f32x4)0.f;
}

// ---------------------------------------------------------------------------
// xl/xr GEMM, y-merged: A = [state(f32)|inp] fragments loaded ONCE per wave,
// then two weight units (Wl, Wr) run back-to-back from registers.
// ---------------------------------------------------------------------------
__global__ __launch_bounds__(256, 4)
void gemm_xlxr_k(const float* __restrict__ state, const float* __restrict__ inp,
                 const f16* __restrict__ Wp,
                 f16* __restrict__ xl, f16* __restrict__ xr, int M)
{
    const int tid = threadIdx.x;
    const int w = tid >> 6, l = tid & 63, lr = l & 15, lk = l >> 4;
    const int rb = blockIdx.x * 128 + w * 32;

    f16x8 af[4][2];
    #pragma unroll
    for (int t = 0; t < 2; ++t) {
        int row = rb + t * 16 + lr; if (row >= M) row = M - 1;
        const float* bf = state + (size_t)row * UU;
        #pragma unroll
        for (int s = 0; s < 3; ++s) {
            const int kb = s * 4 + lk;
            const float4 x0 = *(const float4*)(bf + kb * 8);
            const float4 x1 = *(const float4*)(bf + kb * 8 + 4);
            f16x8 v;
            v[0]=(f16)x0.x; v[1]=(f16)x0.y; v[2]=(f16)x0.z; v[3]=(f16)x0.w;
            v[4]=(f16)x1.x; v[5]=(f16)x1.y; v[6]=(f16)x1.z; v[7]=(f16)x1.w;
            af[s][t] = v;
        }
        f16x8 v = (f16x8)(f16)0.f;
        if (lk == 0) {
            const float4 x0 = *(const float4*)(bf + 96);
            v[0]=(f16)x0.x; v[1]=(f16)x0.y; v[2]=(f16)x0.z; v[3]=(f16)x0.w;
            v[4] = (f16)inp[(size_t)row * DD + 0];
            v[5] = (f16)inp[(size_t)row * DD + 1];
            v[6] = (f16)inp[(size_t)row * DD + 2];
            v[7] = (f16)0.f;
        }
        af[3][t] = v;
    }

    f32x4 acc[2][7];

    acc_zero(acc);
    mma_unit(af, Wp, l, acc);
    #pragma unroll
    for (int t = 0; t < 2; ++t)
        #pragma unroll
        for (int j = 0; j < 7; ++j) {
            const int col = j * 16 + lr;
            if (col >= UU) continue;
            #pragma unroll
            for (int r = 0; r < 4; ++r) {
                const int row = rb + t * 16 + lk * 4 + r;
                if (row < M) xl[(size_t)row * UP + col] = (f16)acc[t][j][r];
            }
        }

    acc_zero(acc);
    mma_unit(af, Wp + UNIT_W, l, acc);
    #pragma unroll
    for (int t = 0; t < 2; ++t)
        #pragma unroll
        for (int j = 0; j < 7; ++j) {
            const int col = j * 16 + lr;
            if (col >= UU) continue;
            #pragma unroll
            for (int r = 0; r < 4; ++r) {
                const int row = rb + t * 16 + lk * 4 + r;
                if (row < M) xr[(size_t)row * UP + col] = (f16)acc[t][j][r];
            }
        }
}

// ---------------------------------------------------------------------------
// Fused GRU: r-gate, u-gate, gru2 and final output in ONE kernel.
// Phase 1: A(st,inp) fragments -> MFMA unit2 -> rst into LDS (C-layout),
//          MFMA unit3 -> u into LDS; inp cols appended to rst rows.
// Phase 2: rst re-read as A-fragments from LDS -> MFMA unit4 ->
//          out = u*st + (1-u)*tanh(.)  (f32, d_out).
// LDS 53 KB -> 3 blocks/CU.
// ---------------------------------------------------------------------------
__global__ __launch_bounds__(256, 3)
void gru_fused_k(const f16* __restrict__ st, const float* __restrict__ inp,
                 const f16* __restrict__ Wp /* unit2 base */,
                 const float* __restrict__ bg1, const float* __restrict__ bg2,
                 float* __restrict__ out, int M)
{
    __shared__ f16 rst_s[128 * UP];   // 26624 B, C-layout [localrow][col]
    __shared__ f16 u_s[128 * UP];     // 26624 B

    const int tid = threadIdx.x;
    const int w = tid >> 6, l = tid & 63, lr = l & 15, lk = l >> 4;
    const int rb = blockIdx.x * 128 + w * 32;

    // ---- phase 1: A fragments from st (f16, UP stride) + inp ----
    f16x8 af[4][2];
    #pragma unroll
    for (int t = 0; t < 2; ++t) {
        int row = rb + t * 16 + lr; if (row >= M) row = M - 1;
        const f16* bh = st + (size_t)row * UP;
        #pragma unroll
        for (int s = 0; s < 3; ++s)
            af[s][t] = *(const f16x8*)(bh + (s * 4 + lk) * 8);
        f16x8 v = (f16x8)(f16)0.f;
        if (lk == 0) {
            v = *(const f16x8*)(bh + 96);      // 96..99 real, 100..103 pad
            v[4] = (f16)inp[(size_t)row * DD + 0];
            v[5] = (f16)inp[(size_t)row * DD + 1];
            v[6] = (f16)inp[(size_t)row * DD + 2];
            v[7] = (f16)0.f;
        }
        af[3][t] = v;
    }

    f32x4 acc[2][7];

    // ---- r-gate: rst = sigmoid(acc + bg1[col]) * st  -> LDS ----
    acc_zero(acc);
    mma_unit(af, Wp, l, acc);
    #pragma unroll
    for (int t = 0; t < 2; ++t)
        #pragma unroll
        for (int j = 0; j < 7; ++j) {
            const int col = j * 16 + lr;
            if (col >= UU) continue;
            const float bR = bg1[col];
            #pragma unroll
            for (int r = 0; r < 4; ++r) {
                const int grow = rb + t * 16 + lk * 4 + r;
                const int lrow = w * 32 + t * 16 + lk * 4 + r;
                if (grow < M) {
                    const float stv = (float)st[(size_t)grow * UP + col];
                    const float sg = 1.f / (1.f + __expf(-(acc[t][j][r] + bR)));
                    rst_s[lrow * UP + col] = (f16)(sg * stv);
                }
            }
        }

    // ---- u-gate: u = sigmoid(acc + bg1[100+col]) -> LDS ----
    acc_zero(acc);
    mma_unit(af, Wp + UNIT_W, l, acc);
    #pragma unroll
    for (int t = 0; t < 2; ++t)
        #pragma unroll
        for (int j = 0; j < 7; ++j) {
            const int col = j * 16 + lr;
            if (col >= UU) continue;
            const float bU = bg1[UU + col];
            #pragma unroll
            for (int r = 0; r < 4; ++r) {
                const int grow = rb + t * 16 + lk * 4 + r;
                const int lrow = w * 32 + t * 16 + lk * 4 + r;
                if (grow < M)
                    u_s[lrow * UP + col] = (f16)(1.f / (1.f + __expf(-(acc[t][j][r] + bU))));
            }
        }

    // ---- inp columns 100..103 of rst rows ----
    if (tid < 128) {
        int grow = blockIdx.x * 128 + tid; if (grow >= M) grow = M - 1;
        rst_s[tid * UP + 100] = (f16)inp[(size_t)grow * DD + 0];
        rst_s[tid * UP + 101] = (f16)inp[(size_t)grow * DD + 1];
        rst_s[tid * UP + 102] = (f16)inp[(size_t)grow * DD + 2];
        rst_s[tid * UP + 103] = (f16)0.f;
    }
    __syncthreads();

    // ---- phase 2: rst A-fragments from LDS, MFMA unit4 ----
    f16x8 af2[4][2];
    #pragma unroll
    for (int t = 0; t < 2; ++t) {
        const int lrow = w * 32 + t * 16 + lr;
        #pragma unroll
        for (int s = 0; s < 3; ++s)
            af2[s][t] = *(const f16x8*)&rst_s[lrow * UP + (s * 4 + lk) * 8];
        af2[3][t] = (lk == 0) ? *(const f16x8*)&rst_s[lrow * UP + 96]
                              : (f16x8)(f16)0.f;
    }
    acc_zero(acc);
    mma_unit(af2, Wp + 2 * UNIT_W, l, acc);

    // ---- final: out = u*st + (1-u)*tanh(acc + bg2[col]) ----
    #pragma unroll
    for (int t = 0; t < 2; ++t)
        #pragma unroll
        for (int j = 0; j < 7; ++j) {
            const int col = j * 16 + lr;
            if (col >= UU) continue;
            const float bC = bg2[col];
            #pragma unroll
            for (int r = 0; r < 4; ++r) {
                const int grow = rb + t * 16 + lk * 4 + r;
                const int lrow = w * 32 + t * 16 + lk * 4 + r;
                if (grow < M) {
                    const float c = tanhf(acc[t][j][r] + bC);
                    const float u = (float)u_s[lrow * UP + col];
                    const float stv = (float)st[(size_t)grow * UP + col];
                    out[(size_t)grow * UU + col] = u * stv + (1.f - u) * c;
                }
            }
        }
}

// ---------------------------------------------------------------------------
extern "C" void kernel_launch(void* const* d_in, const int* in_sizes, int n_in,
                              void* d_out, int out_size, void* d_ws, size_t ws_size,
                              hipStream_t stream)
{
    const float* inputs   = (const float*)d_in[0];
    const float* state    = (const float*)d_in[1];
    const int*   src      = (const int*)  d_in[2];
    const int*   dst      = (const int*)  d_in[3];
    const float* Wl       = (const float*)d_in[4];
    const float* Wr       = (const float*)d_in[5];
    const float* att      = (const float*)d_in[6];
    const float* gat_bias = (const float*)d_in[7];
    const float* bias_gc  = (const float*)d_in[8];
    const float* Wg1      = (const float*)d_in[9];
    const float* bg1      = (const float*)d_in[10];
    const float* Wg2      = (const float*)d_in[11];
    const float* bg2      = (const float*)d_in[12];

    const int E = in_sizes[2];
    const int B = in_sizes[1] / (NN * UU);
    const int M = B * NN;
    const int Etot = E + NN;

    char* ws = (char*)d_ws;
    const size_t SH = (size_t)M * UP * sizeof(f16);
    f16* xl_h = (f16*)ws;
    f16* xr_h = (f16*)(ws + SH);                      // later reused as st
    f16* Wp   = (f16*)(ws + 2 * SH);
    int* offs = (int*)(ws + 2 * SH + 5 * UNIT_W * sizeof(f16));
    int* eidx = offs + (NN + 1);
    int* ddst = eidx + (Etot + 64);
    f16* st_h = xr_h;                                 // st overwrites xr
    float* out = (float*)d_out;

    const int mb = (M + 127) / 128;

    pack_w_k<<<56, 256, 0, stream>>>(Wl, Wr, Wg1, Wg2, Wp);
    csr_count_k<<<NN, 64, 0, stream>>>(dst, E, offs);
    csr_scan_k<<<1, 64, 0, stream>>>(offs);
    csr_fill_k<<<NN, 64, 0, stream>>>(src, dst, E, offs, eidx, ddst);

    // xl = [state|inputs] @ Wl ; xr = [state|inputs] @ Wr  (one pass over A)
    gemm_xlxr_k<<<mb, 256, 0, stream>>>(state, inputs, Wp, xl_h, xr_h, M);

    // Fused GAT: scores + softmax + aggregate -> st (over xr buffer)
    gat_fused_k<<<B, 1024, 0, stream>>>(xl_h, xr_h, offs, eidx, ddst,
        att, gat_bias, bias_gc, Etot, st_h);

    // Fused GRU: r, u, gru2, final output
    gru_fused_k<<<mb, 256, 0, stream>>>(st_h, inputs, Wp + 2 * (size_t)UNIT_W,
        bg1, bg2, out, M);
}